// Round 12
// baseline (4300.683 us; speedup 1.0000x reference)
//
#include <hip/hip_runtime.h>
#include <hip/hip_bf16.h>

typedef __hip_bfloat16 bf16;
typedef __attribute__((ext_vector_type(8))) short s8v;
typedef __attribute__((ext_vector_type(4))) float f32x4;
typedef __attribute__((ext_vector_type(4))) int int4v;

#define NB 64
#define NS 256
#define ND 512
#define NHE 512
#define NHD 1024
#define NGE 1536
#define NGD 3072

static __device__ __forceinline__ float sigmf(float x){ return 1.0f/(1.0f+__expf(-x)); }
static __device__ __forceinline__ float b2f(unsigned short u){ return __uint_as_float(((unsigned int)u) << 16); }
static __device__ __forceinline__ unsigned short f2bu(float f){
    bf16 v = __float2bfloat16(f);
    return *reinterpret_cast<unsigned short*>(&v);
}
static __device__ __forceinline__ s8v cast8(int4v v){
    union { int4v i; s8v s; } u; u.i = v; return u.s;
}
// LLC-coherent 2-byte store (bypass L1/L2 -> memory-side Infinity Cache)
static __device__ __forceinline__ void st2_llc(const void* p, unsigned int v){
    asm volatile("global_store_short %0, %1, off sc0 sc1"
                 :: "v"((unsigned long long)(uintptr_t)p), "v"(v) : "memory");
}

// 8x 16B LLC-coherent loads + drain.
#define LOADX8(BASEP, A0,A1,A2,A3,A4,A5,A6,A7)                                   \
    asm volatile(                                                                \
        "global_load_dwordx4 %0, %8, off sc0 sc1\n\t"                            \
        "global_load_dwordx4 %1, %8, off offset:64 sc0 sc1\n\t"                  \
        "global_load_dwordx4 %2, %8, off offset:128 sc0 sc1\n\t"                 \
        "global_load_dwordx4 %3, %8, off offset:192 sc0 sc1\n\t"                 \
        "global_load_dwordx4 %4, %8, off offset:256 sc0 sc1\n\t"                 \
        "global_load_dwordx4 %5, %8, off offset:320 sc0 sc1\n\t"                 \
        "global_load_dwordx4 %6, %8, off offset:384 sc0 sc1\n\t"                 \
        "global_load_dwordx4 %7, %8, off offset:448 sc0 sc1\n\t"                 \
        "s_waitcnt vmcnt(0)"                                                     \
        : "=&v"(A0),"=&v"(A1),"=&v"(A2),"=&v"(A3),                               \
          "=&v"(A4),"=&v"(A5),"=&v"(A6),"=&v"(A7)                                \
        : "v"((unsigned long long)(uintptr_t)(BASEP)) : "memory");               \
    __builtin_amdgcn_sched_barrier(0);

// ---------------- small prep kernels ----------------
__global__ __launch_bounds__(256) void k_sx(const float* __restrict__ x,
                                            const float* __restrict__ attnW,
                                            const float* __restrict__ attnb,
                                            float* __restrict__ sx){
    int row = blockIdx.x*4 + (threadIdx.x>>6);
    int lane = threadIdx.x & 63;
    float s = 0.f;
    for (int d = lane; d < ND; d += 64) s += x[(size_t)row*ND + d]*attnW[d];
    #pragma unroll
    for (int off = 32; off; off >>= 1) s += __shfl_down(s, off, 64);
    if (lane == 0) sx[row] = s + attnb[0];
}

__global__ __launch_bounds__(256) void k_cvec(const float* __restrict__ dWih,
                                              const float* __restrict__ linb,
                                              const float* __restrict__ dbih,
                                              float* __restrict__ cvec){
    int row = blockIdx.x*4 + (threadIdx.x>>6);
    int lane = threadIdx.x & 63;
    float s = 0.f;
    for (int d = lane; d < ND; d += 64) s += dWih[(size_t)row*ND + d]*linb[d];
    #pragma unroll
    for (int off = 32; off; off >>= 1) s += __shfl_down(s, off, 64);
    if (lane == 0) cvec[row] = s + dbih[row];
}

__global__ __launch_bounds__(256) void k_softprep2(const float* __restrict__ sx,
                                                   float* __restrict__ esb,
                                                   float* __restrict__ Se){
    int b = blockIdx.x, s = threadIdx.x;
    __shared__ float red[256];
    float v = sx[b*NS + s];
    red[s] = v; __syncthreads();
    for (int off = 128; off; off >>= 1){ if (s < off) red[s] = fmaxf(red[s], red[s+off]); __syncthreads(); }
    float mx = red[0]; __syncthreads();
    float ev = __expf(v - mx);
    esb[s*NB + b] = ev;
    red[s] = ev; __syncthreads();
    for (int off = 128; off; off >>= 1){ if (s < off) red[s] += red[s+off]; __syncthreads(); }
    if (s == 0) Se[b] = red[0];
}

__global__ __launch_bounds__(256) void k_cvtW(const float* __restrict__ W, bf16* __restrict__ o){
    size_t i = ((size_t)blockIdx.x*256 + threadIdx.x)*4;
    float4 v = *(const float4*)(W + i);
    o[i+0] = __float2bfloat16(v.x);
    o[i+1] = __float2bfloat16(v.y);
    o[i+2] = __float2bfloat16(v.z);
    o[i+3] = __float2bfloat16(v.w);
}

// z[t][h][b] from bf16 history hxh[dir][t][b][j]
__global__ __launch_bounds__(256) void k_zexp3(const bf16* __restrict__ hxh,
                                               const float* __restrict__ eps,
                                               bf16* __restrict__ z){
    int t  = blockIdx.x >> 4;
    int hb = blockIdx.x & 15;
    int dmu = hb >> 3;
    int jm0 = (hb & 7)*64;
    const unsigned short* hu = (const unsigned short*)hxh;
    __shared__ unsigned short zt[64][66];
    int tid = threadIdx.x;
    #pragma unroll
    for (int q = 0; q < 16; ++q){
        int bb = q*4 + (tid>>6);
        int hc = tid & 63;
        float mu = b2f(hu[(((size_t)(dmu*NS) + t)*64 + bb)*512 + jm0 + hc]);
        float lv = b2f(hu[(((size_t)((2+dmu)*NS) + t)*64 + bb)*512 + jm0 + hc]);
        float ep = eps[((size_t)bb*NS + t)*NHD + hb*64 + hc];
        zt[bb][hc] = f2bu(mu + ep*__expf(0.5f*lv));
    }
    __syncthreads();
    unsigned short* zu = (unsigned short*)z;
    int b = tid & 63;
    #pragma unroll
    for (int q = 0; q < 16; ++q){
        int hl = q*4 + (tid>>6);
        zu[((size_t)t*NHD + hb*64 + hl)*NB + b] = zt[b][hl];
    }
}

// mu/logvar outputs: coalesced copy from hxh[dir][t][b][j]
__global__ __launch_bounds__(256) void k_outT2(const bf16* __restrict__ hxh,
                                               float* __restrict__ outMu,
                                               float* __restrict__ outLv){
    int t  = blockIdx.x;
    int b0 = blockIdx.y*8;
    const unsigned short* hu = (const unsigned short*)hxh;
    int tid = threadIdx.x;
    #pragma unroll
    for (int q = 0; q < 16; ++q){
        int idx = q*256 + tid;
        int sel = idx >> 11;           // 0=mu 1=lv
        int rem = idx & 2047;
        int bb  = b0 + (rem >> 8);
        int h   = (rem & 255)*4;
        int dirn = (h >> 9) + sel*2;
        int j   = h & 511;
        ushort4 v = *(const ushort4*)(hu + (((size_t)(dirn*NS) + t)*64 + bb)*512 + j);
        float4 o;
        o.x = b2f(v.x); o.y = b2f(v.y); o.z = b2f(v.z); o.w = b2f(v.w);
        float* outp = sel ? outLv : outMu;
        *(float4*)(outp + ((size_t)bb*NS + t)*NHD + h) = o;
    }
}

__global__ __launch_bounds__(256) void k_T2(const bf16* __restrict__ z,
                                            const float* __restrict__ esb,
                                            float* __restrict__ T){
    int h = blockIdx.x;
    int b = threadIdx.x & 63;
    int sq = threadIdx.x >> 6;
    __shared__ float red[4][64];
    float acc = 0.f;
    #pragma unroll 8
    for (int s = sq*64; s < sq*64 + 64; ++s)
        acc += esb[s*NB + b]*__bfloat162float(z[((size_t)s*NHD + h)*NB + b]);
    red[sq][b] = acc; __syncthreads();
    if (sq == 0) T[h*NB + b] = red[0][b] + red[1][b] + red[2][b] + red[3][b];
}

__global__ __launch_bounds__(256) void k_ctx3(const bf16* __restrict__ z,
                                              const float* __restrict__ esb,
                                              const float* __restrict__ Se,
                                              const float* __restrict__ T,
                                              bf16* __restrict__ ctxT,
                                              bf16* __restrict__ ctxB){
    int i  = blockIdx.x >> 4;
    int hb = blockIdx.x & 15;
    int tid = threadIdx.x;
    int b  = tid & 63;
    __shared__ unsigned short tt[64][66];
    float ei  = esb[i*NB + b];
    float inv = 1.0f/(Se[b] - ei);
    #pragma unroll
    for (int q = 0; q < 16; ++q){
        int hl = q*4 + (tid>>6);
        int h = hb*64 + hl;
        float zv = __bfloat162float(z[((size_t)i*NHD + h)*NB + b]);
        float cv = (T[h*NB + b] - ei*zv)*inv;
        unsigned short u = f2bu(cv);
        ctxT[((size_t)i*NHD + h)*NB + b] = *reinterpret_cast<bf16*>(&u);
        tt[hl][b] = u;
    }
    __syncthreads();
    unsigned short* cb = (unsigned short*)ctxB;
    #pragma unroll
    for (int q = 0; q < 16; ++q){
        int bn = q*4 + (tid>>6);
        int hl = tid & 63;
        cb[((size_t)i*NB + bn)*NHD + hb*64 + hl] = tt[hl][bn];
    }
}

__global__ __launch_bounds__(256) void k_gemm_M(
    const float* __restrict__ dWih,
    const float* __restrict__ linW,
    bf16* __restrict__ M){
    int g0 = blockIdx.x*64;
    int h0 = blockIdx.y*64;
    __shared__ float As[64][36];
    __shared__ float Bs[32][68];
    int tid = threadIdx.x, tx = tid & 15, ty = tid >> 4;
    float acc[4][4] = {};
    for (int k0 = 0; k0 < ND; k0 += 32){
        #pragma unroll
        for (int m = 0; m < 8; ++m){
            int idx = m*256 + tid;
            int row = idx >> 5, kk = idx & 31;
            As[row][kk] = dWih[(size_t)(g0+row)*ND + k0 + kk];
            int k2 = idx >> 6, hh2 = idx & 63;
            Bs[k2][hh2] = linW[(size_t)(k0+k2)*NHD + h0 + hh2];
        }
        __syncthreads();
        for (int k = 0; k < 32; ++k){
            float a[4];
            #pragma unroll
            for (int i = 0; i < 4; ++i) a[i] = As[ty*4+i][k];
            float4 b4 = *(const float4*)&Bs[k][tx*4];
            #pragma unroll
            for (int i = 0; i < 4; ++i){
                acc[i][0] += a[i]*b4.x; acc[i][1] += a[i]*b4.y;
                acc[i][2] += a[i]*b4.z; acc[i][3] += a[i]*b4.w;
            }
        }
        __syncthreads();
    }
    #pragma unroll
    for (int i = 0; i < 4; ++i)
        #pragma unroll
        for (int j = 0; j < 4; ++j)
            M[(size_t)(g0+ty*4+i)*NHD + h0 + tx*4 + j] = __float2bfloat16(acc[i][j]);
}

// ---------------- MFMA prep GEMMs ----------------
__global__ __launch_bounds__(256, 2) void k_xg_mfma(
    const bf16* __restrict__ xb,     // [64][256][512]
    const bf16* __restrict__ WihB,   // [4][1536][512]
    const float* __restrict__ b0, const float* __restrict__ b1,
    const float* __restrict__ b2, const float* __restrict__ b3,
    bf16* __restrict__ Xg){
    int t = blockIdx.x, gblk = blockIdx.y, dir = blockIdx.z;
    const float* bih = dir==0?b0:dir==1?b1:dir==2?b2:b3;
    int tid = threadIdx.x;
    int lane = tid & 63;
    int w = __builtin_amdgcn_readfirstlane(tid >> 6);
    int ln = lane & 15, lk = lane >> 4;
    int g = gblk*64 + w*16 + ln;
    const unsigned short* Bp = (const unsigned short*)WihB + ((size_t)(dir*NGE + g))*512 + lk*8;
    s8v Bf[16];
    #pragma unroll
    for (int q = 0; q < 16; ++q) Bf[q] = *(const s8v*)(Bp + q*32);
    f32x4 C[4] = {};
    const unsigned short* xu = (const unsigned short*)xb;
    #pragma unroll
    for (int m = 0; m < 4; ++m){
        const unsigned short* Ap = xu + ((size_t)(m*16+ln)*NS + t)*ND + lk*8;
        #pragma unroll
        for (int q = 0; q < 16; ++q){
            s8v Af = *(const s8v*)(Ap + q*32);
            C[m] = __builtin_amdgcn_mfma_f32_16x16x32_bf16(Af, Bf[q], C[m], 0, 0, 0);
        }
    }
    float bi = bih[g];
    unsigned short* Op = (unsigned short*)Xg + ((size_t)(dir*NS + t)*NGE + g)*NB;
    #pragma unroll
    for (int m = 0; m < 4; ++m){
        ushort4 o;
        o.x = f2bu(C[m][0] + bi); o.y = f2bu(C[m][1] + bi);
        o.z = f2bu(C[m][2] + bi); o.w = f2bu(C[m][3] + bi);
        *(ushort4*)(Op + m*16 + lk*4) = o;
    }
}

__global__ __launch_bounds__(256, 2) void k_gctx_mfma(
    const bf16* __restrict__ ctxB,   // [256][64][1024]
    const bf16* __restrict__ dWhhB,  // [3072][1024]
    const float* __restrict__ bhh,
    bf16* __restrict__ Gctx){
    int i = blockIdx.x, gblk = blockIdx.y;
    int tid = threadIdx.x;
    int lane = tid & 63;
    int w = __builtin_amdgcn_readfirstlane(tid >> 6);
    int ln = lane & 15, lk = lane >> 4;
    int g = gblk*64 + w*16 + ln;
    f32x4 C[4] = {};
    const unsigned short* cu = (const unsigned short*)ctxB;
    const unsigned short* wu = (const unsigned short*)dWhhB;
    #pragma unroll
    for (int kc = 0; kc < 2; ++kc){
        const unsigned short* Bp = wu + (size_t)g*NHD + kc*512 + lk*8;
        s8v Bf[16];
        #pragma unroll
        for (int q = 0; q < 16; ++q) Bf[q] = *(const s8v*)(Bp + q*32);
        #pragma unroll
        for (int m = 0; m < 4; ++m){
            const unsigned short* Ap = cu + ((size_t)i*NB + m*16+ln)*NHD + kc*512 + lk*8;
            #pragma unroll
            for (int q = 0; q < 16; ++q){
                s8v Af = *(const s8v*)(Ap + q*32);
                C[m] = __builtin_amdgcn_mfma_f32_16x16x32_bf16(Af, Bf[q], C[m], 0, 0, 0);
            }
        }
    }
    float bi = bhh[g];
    unsigned short* Op = (unsigned short*)Gctx + ((size_t)i*NGD + g)*NB;
    #pragma unroll
    for (int m = 0; m < 4; ++m){
        ushort4 o;
        o.x = f2bu(C[m][0] + bi); o.y = f2bu(C[m][1] + bi);
        o.z = f2bu(C[m][2] + bi); o.w = f2bu(C[m][3] + bi);
        *(ushort4*)(Op + m*16 + lk*4) = o;
    }
}

__global__ __launch_bounds__(256, 2) void k_rec_mfma(
    const bf16* __restrict__ Ht,     // [256][64][1024]
    const bf16* __restrict__ linWB,  // [512][1024]
    const float* __restrict__ linb,
    float* __restrict__ outRec){
    int i = blockIdx.x, dblk = blockIdx.y;
    int tid = threadIdx.x;
    int lane = tid & 63;
    int w = __builtin_amdgcn_readfirstlane(tid >> 6);
    int ln = lane & 15, lk = lane >> 4;
    int d = dblk*64 + w*16 + ln;
    f32x4 C[4] = {};
    const unsigned short* hu = (const unsigned short*)Ht;
    const unsigned short* wu = (const unsigned short*)linWB;
    #pragma unroll
    for (int kc = 0; kc < 2; ++kc){
        const unsigned short* Bp = wu + (size_t)d*NHD + kc*512 + lk*8;
        s8v Bf[16];
        #pragma unroll
        for (int q = 0; q < 16; ++q) Bf[q] = *(const s8v*)(Bp + q*32);
        #pragma unroll
        for (int m = 0; m < 4; ++m){
            const unsigned short* Ap = hu + ((size_t)i*NB + m*16+ln)*NHD + kc*512 + lk*8;
            #pragma unroll
            for (int q = 0; q < 16; ++q){
                s8v Af = *(const s8v*)(Ap + q*32);
                C[m] = __builtin_amdgcn_mfma_f32_16x16x32_bf16(Af, Bf[q], C[m], 0, 0, 0);
            }
        }
    }
    float lb = linb[d];
    #pragma unroll
    for (int m = 0; m < 4; ++m)
        #pragma unroll
        for (int r = 0; r < 4; ++r){
            int b = m*16 + lk*4 + r;
            outRec[((size_t)b*NS + i)*ND + d] = C[m][r] + lb;
        }
}

// ---------------- MFMA recurrence kernels (flag-sync, LLC exchange) ----------------
__global__ __launch_bounds__(256, 1) void k_enc12(
    const bf16* __restrict__ Xg,
    const bf16* __restrict__ WB,     // [4][1536][512] bf16
    const float* __restrict__ b0, const float* __restrict__ b1,
    const float* __restrict__ b2, const float* __restrict__ b3,
    bf16* __restrict__ hxh,          // [4][256][64][512] bf16 (history == exchange)
    unsigned int* __restrict__ flagE){
    int wg  = blockIdx.x;
    int grp = wg & 15;
    int wl  = wg >> 4;
    int dir = grp >> 2;
    int bq  = grp & 3;
    int tid = threadIdx.x;
    int lane = tid & 63;
    int wid = __builtin_amdgcn_readfirstlane(tid >> 6);
    int jl = wid & 1, kh = wid >> 1;
    int jt = wl*2 + jl;
    int ln = lane & 15, lk = lane >> 4;
    int j  = jt*16 + ln;
    int b0v = bq*16 + lk*4;
    const float* bhh = dir==0?b0:dir==1?b1:dir==2?b2:b3;
    const unsigned short* WBu = (const unsigned short*)WB;
    s8v Bf[3][8];
    #pragma unroll
    for (int g = 0; g < 3; ++g)
        #pragma unroll
        for (int q = 0; q < 8; ++q)
            Bf[g][q] = *(const s8v*)(WBu + ((size_t)(dir*NGE + g*512 + j))*512 + (kh*8+q)*32 + lk*8);
    float br=0.f, bz=0.f, bn=0.f;
    if (kh == 0){ br = bhh[j]; bz = bhh[j+512]; bn = bhh[j+1024]; }
    float hp0=0.f, hp1=0.f, hp2=0.f, hp3=0.f;
    __shared__ float red[2][3][64][4];
    unsigned int* fg = flagE + grp*16;
    const unsigned short* Xgu = (const unsigned short*)Xg;
    const unsigned short* hu = (const unsigned short*)hxh;
    ushort4 xr, xz, xn;
    if (kh == 0){
        int t0 = (dir & 1) ? 255 : 0;
        size_t xb_ = (size_t)(dir*NS + t0)*NGE;
        xr = *(const ushort4*)(Xgu + (xb_ + j)*NB + b0v);
        xz = *(const ushort4*)(Xgu + (xb_ + j + 512)*NB + b0v);
        xn = *(const ushort4*)(Xgu + (xb_ + j + 1024)*NB + b0v);
    }
    for (int t = 0; t < NS; ++t){
        int tcur = (dir & 1) ? (255 - t) : t;
        f32x4 C0 = {0.f,0.f,0.f,0.f}, C1 = {0.f,0.f,0.f,0.f}, C2 = {0.f,0.f,0.f,0.f};
        if (t > 0){
            int tprev = (dir & 1) ? (256 - t) : (t - 1);
            const unsigned short* hxr = hu
                + (((size_t)(dir*NS + tprev))*64 + bq*16 + ln)*512 + kh*256 + lk*8;
            int4v a0,a1,a2,a3,a4,a5,a6,a7;
            LOADX8(hxr, a0,a1,a2,a3,a4,a5,a6,a7)
            s8v Af;
            #define MF3(AV) Af = cast8(AV); \
                C0 = __builtin_amdgcn_mfma_f32_16x16x32_bf16(Af, Bf[0][__q], C0, 0, 0, 0); \
                C1 = __builtin_amdgcn_mfma_f32_16x16x32_bf16(Af, Bf[1][__q], C1, 0, 0, 0); \
                C2 = __builtin_amdgcn_mfma_f32_16x16x32_bf16(Af, Bf[2][__q], C2, 0, 0, 0);
            { enum {__q=0}; MF3(a0) } { enum {__q=1}; MF3(a1) }
            { enum {__q=2}; MF3(a2) } { enum {__q=3}; MF3(a3) }
            { enum {__q=4}; MF3(a4) } { enum {__q=5}; MF3(a5) }
            { enum {__q=6}; MF3(a6) } { enum {__q=7}; MF3(a7) }
            #undef MF3
        }
        if (kh == 1){
            *(f32x4*)&red[jl][0][lane][0] = C0;
            *(f32x4*)&red[jl][1][lane][0] = C1;
            *(f32x4*)&red[jl][2][lane][0] = C2;
        }
        __syncthreads();
        if (kh == 0){
            C0 += *(const f32x4*)&red[jl][0][lane][0];
            C1 += *(const f32x4*)&red[jl][1][lane][0];
            C2 += *(const f32x4*)&red[jl][2][lane][0];
            {
                float r_ = sigmf(b2f(xr.x) + C0[0] + br);
                float z_ = sigmf(b2f(xz.x) + C1[0] + bz);
                float n_ = tanhf(b2f(xn.x) + r_*(C2[0] + bn));
                hp0 = (1.f - z_)*n_ + z_*hp0;
            }
            {
                float r_ = sigmf(b2f(xr.y) + C0[1] + br);
                float z_ = sigmf(b2f(xz.y) + C1[1] + bz);
                float n_ = tanhf(b2f(xn.y) + r_*(C2[1] + bn));
                hp1 = (1.f - z_)*n_ + z_*hp1;
            }
            {
                float r_ = sigmf(b2f(xr.z) + C0[2] + br);
                float z_ = sigmf(b2f(xz.z) + C1[2] + bz);
                float n_ = tanhf(b2f(xn.z) + r_*(C2[2] + bn));
                hp2 = (1.f - z_)*n_ + z_*hp2;
            }
            {
                float r_ = sigmf(b2f(xr.w) + C0[3] + br);
                float z_ = sigmf(b2f(xz.w) + C1[3] + bz);
                float n_ = tanhf(b2f(xn.w) + r_*(C2[3] + bn));
                hp3 = (1.f - z_)*n_ + z_*hp3;
            }
            const unsigned short* hw = hu + ((size_t)(dir*NS + tcur))*64*512;
            st2_llc(hw + (size_t)(b0v+0)*512 + j, (unsigned int)f2bu(hp0));
            st2_llc(hw + (size_t)(b0v+1)*512 + j, (unsigned int)f2bu(hp1));
            st2_llc(hw + (size_t)(b0v+2)*512 + j, (unsigned int)f2bu(hp2));
            st2_llc(hw + (size_t)(b0v+3)*512 + j, (unsigned int)f2bu(hp3));
            if (t < NS-1){   // prefetch next step's read-only gates (cached loads)
                int tn = (dir & 1) ? (254 - t) : (t + 1);
                size_t xb_ = (size_t)(dir*NS + tn)*NGE;
                xr = *(const ushort4*)(Xgu + (xb_ + j)*NB + b0v);
                xz = *(const ushort4*)(Xgu + (xb_ + j + 512)*NB + b0v);
                xn = *(const ushort4*)(Xgu + (xb_ + j + 1024)*NB + b0v);
            }
        }
        __syncthreads();   // drains ALL waves' vmem -> exchange data visible in LLC
        if (t < NS-1){
            if (tid == 0)
                __hip_atomic_store(fg + wl, (unsigned int)(t+1), __ATOMIC_RELAXED, __HIP_MEMORY_SCOPE_AGENT);
            if (wid == 0){
                int src = lane & 15;
                while (!__all((int)__hip_atomic_load(fg + src, __ATOMIC_RELAXED, __HIP_MEMORY_SCOPE_AGENT) >= t+1))
                    __builtin_amdgcn_s_sleep(1);
            }
            __syncthreads();
        }
    }
}

__global__ __launch_bounds__(256, 1) void k_dec12(
    const bf16* __restrict__ MB,     // [3072][1024] bf16
    const float* __restrict__ cvec,
    const float* __restrict__ dbih,
    const bf16* __restrict__ Gctx,
    const bf16* __restrict__ ctxT,
    bf16* __restrict__ Ht,           // [256][64][1024] bf16 history (LLC-coherent)
    unsigned int* __restrict__ flagD){
    int wg  = blockIdx.x;
    int grp = wg & 3;
    int jt  = wg >> 2;
    int tid = threadIdx.x;
    int lane = tid & 63;
    int wid = __builtin_amdgcn_readfirstlane(tid >> 6);
    int ln = lane & 15, lk = lane >> 4;
    int j  = jt*16 + ln;
    int b0v = grp*16 + lk*4;
    const unsigned short* MBu = (const unsigned short*)MB;
    s8v Bf[3][8];
    #pragma unroll
    for (int g = 0; g < 3; ++g)
        #pragma unroll
        for (int q = 0; q < 8; ++q)
            Bf[g][q] = *(const s8v*)(MBu + ((size_t)(g*NHD + j))*NHD + wid*256 + q*32 + lk*8);
    float c0=0.f,c1=0.f,c2=0.f,d0v=0.f,d1v=0.f,d2v=0.f;
    if (wid == 0){
        c0 = cvec[j]; c1 = cvec[j+NHD]; c2 = cvec[j+2*NHD];
        d0v = dbih[j]; d1v = dbih[j+NHD]; d2v = dbih[j+2*NHD];
    }
    __shared__ float red[3][3][64][4];
    unsigned int* fg = flagD + grp*64;
    const unsigned short* Gu = (const unsigned short*)Gctx;
    const unsigned short* Cu = (const unsigned short*)ctxT;
    const unsigned short* hu = (const unsigned short*)Ht;
    ushort4 gr, gz, gn, cx;
    if (wid == 0){
        gr = *(const ushort4*)(Gu + (size_t)j*NB + b0v);
        gz = *(const ushort4*)(Gu + (size_t)(j+NHD)*NB + b0v);
        gn = *(const ushort4*)(Gu + (size_t)(j+2*NHD)*NB + b0v);
        cx = *(const ushort4*)(Cu + (size_t)j*NB + b0v);
    }
    for (int i = 0; i < NS; ++i){
        f32x4 C0 = {0.f,0.f,0.f,0.f}, C1 = {0.f,0.f,0.f,0.f}, C2 = {0.f,0.f,0.f,0.f};
        if (i > 0){
            const unsigned short* hxr = hu
                + ((size_t)(i-1)*NB + grp*16 + ln)*NHD + wid*256 + lk*8;
            int4v a0,a1,a2,a3,a4,a5,a6,a7;
            LOADX8(hxr, a0,a1,a2,a3,a4,a5,a6,a7)
            s8v Af;
            #define MF3(AV) Af = cast8(AV); \
                C0 = __builtin_amdgcn_mfma_f32_16x16x32_bf16(Af, Bf[0][__q], C0, 0, 0, 0); \
                C1 = __builtin_amdgcn_mfma_f32_16x16x32_bf16(Af, Bf[1][__q], C1, 0, 0, 0); \
                C2 = __builtin_amdgcn_mfma_f32_16x16x32_bf16(Af, Bf[2][__q], C2, 0, 0, 0);
            { enum {__q=0}; MF3(a0) } { enum {__q=1}; MF3(a1) }
            { enum {__q=2}; MF3(a2) } { enum {__q=3}; MF3(a3) }
            { enum {__q=4}; MF3(a4) } { enum {__q=5}; MF3(a5) }
            { enum {__q=6}; MF3(a6) } { enum {__q=7}; MF3(a7) }
            #undef MF3
        }
        if (wid != 0){
            *(f32x4*)&red[wid-1][0][lane][0] = C0;
            *(f32x4*)&red[wid-1][1][lane][0] = C1;
            *(f32x4*)&red[wid-1][2][lane][0] = C2;
        }
        __syncthreads();
        if (wid == 0){
            #pragma unroll
            for (int w = 0; w < 3; ++w){
                C0 += *(const f32x4*)&red[w][0][lane][0];
                C1 += *(const f32x4*)&red[w][1][lane][0];
                C2 += *(const f32x4*)&red[w][2][lane][0];
            }
            f32x4 ho;
            {
                float g0v = (i==0) ? d0v : C0[0] + c0;
                float g1v = (i==0) ? d1v : C1[0] + c1;
                float g2v = (i==0) ? d2v : C2[0] + c2;
                float r_ = sigmf(g0v + b2f(gr.x));
                float z_ = sigmf(g1v + b2f(gz.x));
                float n_ = tanhf(g2v + r_*b2f(gn.x));
                ho[0] = (1.f - z_)*n_ + z_*b2f(cx.x);
            }
            {
                float g0v = (i==0) ? d0v : C0[1] + c0;
                float g1v = (i==0) ? d1v : C1[1] + c1;
                float g2v = (i==0) ? d2v : C2[1] + c2;
                float r_ = sigmf(g0v + b2f(gr.y));
                float z_ = sigmf(g1v + b2f(gz.y));
                float n_ = tanhf(g2v + r_*b2f(gn.y));
                ho[1] = (1.f - z_)*n_ + z_*b2f(cx.y);
            }
            {
                float g0v = (i==0) ? d0v : C0[2] + c0;
                float g1v = (i==0) ? d1v : C1[2] + c1;
                float g2v = (i==0) ? d2v : C2[2] + c2;
                float r_ = sigmf(g0v + b2f(gr.z));
                float z_ = sigmf(g1v + b2f(gz.z));
                float n_ = tanhf(g2v + r_*b2f(gn.z));
                ho[2] = (1.f - z_)*n_ + z_*b2f(cx.z);
            }
            {
                float g0v = (i==0) ? d0v : C0[3] + c0;
                float g1v = (i==0) ? d1v : C1[3] + c1;
                float g2v = (i==0) ? d2v : C2[3] + c2;
                float r_ = sigmf(g0v + b2f(gr.w));
                float z_ = sigmf(g1v + b2f(gz.w));
                float n_ = tanhf(g2v + r_*b2f(gn.w));
                ho[3] = (1.f - z_)*n_ + z_*b2f(cx.w);
            }
            const unsigned short* hw = hu + (size_t)i*NB*NHD;
            st2_llc(hw + (size_t)(b0v+0)*NHD + j, (unsigned int)f2bu(ho[0]));
            st2_llc(hw + (size_t)(b0v+1)*NHD + j, (unsigned int)f2bu(ho[1]));
            st2_llc(hw + (size_t)(b0v+2)*NHD + j, (unsigned int)f2bu(ho[2]));
            st2_llc(hw + (size_t)(b0v+3)*NHD + j, (unsigned int)f2bu(ho[3]));
            if (i < NS-1){   // prefetch next step's read-only operands (cached)
                size_t gbx = (size_t)(i+1)*NGD*NB;
                gr = *(const ushort4*)(Gu + gbx + (size_t)j*NB + b0v);
                gz = *(const ushort4*)(Gu + gbx + (size_t)(j+NHD)*NB + b0v);
                gn = *(const ushort4*)(Gu + gbx + (size_t)(j+2*NHD)*NB + b0v);
                cx = *(const ushort4*)(Cu + ((size_t)(i+1)*NHD + j)*NB + b0v);
            }
        }
        __syncthreads();   // drain: Ht stores visible in LLC
        if (i < NS-1){
            if (tid == 0)
                __hip_atomic_store(fg + jt, (unsigned int)(i+1), __ATOMIC_RELAXED, __HIP_MEMORY_SCOPE_AGENT);
            if (wid == 0){
                while (!__all((int)__hip_atomic_load(fg + lane, __ATOMIC_RELAXED, __HIP_MEMORY_SCOPE_AGENT) >= i+1))
                    __builtin_amdgcn_s_sleep(1);
            }
            __syncthreads();
        }
    }
}

// ---------------- host launcher ----------------
extern "C" void kernel_launch(void* const* d_in, const int* in_sizes, int n_in,
                              void* d_out, int out_size, void* d_ws, size_t ws_size,
                              hipStream_t stream){
    const float* x   = (const float*)d_in[0];
    const float* eps = (const float*)d_in[1];
    const float* Wih[4]; const float* Whh[4]; const float* bih[4]; const float* bhh[4];
    for (int d = 0; d < 4; ++d){
        Wih[d] = (const float*)d_in[2 + 4*d];
        Whh[d] = (const float*)d_in[3 + 4*d];
        bih[d] = (const float*)d_in[4 + 4*d];
        bhh[d] = (const float*)d_in[5 + 4*d];
    }
    const float* dWih  = (const float*)d_in[18];
    const float* dWhh  = (const float*)d_in[19];
    const float* dbih  = (const float*)d_in[20];
    const float* dbhh  = (const float*)d_in[21];
    const float* attnW = (const float*)d_in[22];
    const float* attnb = (const float*)d_in[23];
    const float* linW  = (const float*)d_in[24];
    const float* linb  = (const float*)d_in[25];

    float* out    = (float*)d_out;
    float* outRec = out;
    float* outMu  = out + 8388608;
    float* outLv  = out + 25165824;

    char* ws = (char*)d_ws;
    // disjoint layout (only Gctx/ctxB reuse the dead Xg region):
    bf16*  Xg    = (bf16*)(ws + 0);              // ph0-1: 201326592
    bf16*  Gctx  = (bf16*)(ws + 0);              // ph2-3: 100663296
    bf16*  ctxB  = (bf16*)(ws + 100663296);      // ph2:   33554432 (inside dead Xg)
    bf16*  hxh   = (bf16*)(ws + 201326592);      // ph1-2: 67108864
    bf16*  zbuf  = (bf16*)(ws + 268435456);      // ph2:   33554432
    bf16*  ctxT  = (bf16*)(ws + 301989888);      // ph2-3: 33554432
    bf16*  Ht    = (bf16*)(ws + 335544320);      // ph3-4: 33554432
    bf16*  xb    = (bf16*)(ws + 369098752);      // ph0:   16777216
    bf16*  WihB  = (bf16*)(ws + 385875968);      // ph0:   6291456
    bf16*  WhhB  = (bf16*)(ws + 392167424);      // ph0-1: 6291456
    bf16*  MbufB = (bf16*)(ws + 398458880);      // 6291456
    bf16*  dWhhB = (bf16*)(ws + 404750336);      // ph2:   6291456
    bf16*  linWB = (bf16*)(ws + 411041792);      // 1048576
    float* sx    = (float*)(ws + 412090368);     // 65536
    float* esb   = (float*)(ws + 412155904);     // 65536
    float* Se    = (float*)(ws + 412221440);     // 4096
    float* Tbuf  = (float*)(ws + 412225536);     // 262144
    float* cvec  = (float*)(ws + 412487680);     // 12288
    unsigned int* flagE = (unsigned int*)(ws + 412499968);  // 1024
    unsigned int* flagD = (unsigned int*)(ws + 412500992);  // 1024

    hipMemsetAsync(ws + 412499968, 0, 8192, stream);

    // phase 0: conversions + statics + Xg (MFMA)
    hipLaunchKernelGGL(k_cvtW, dim3(8192), dim3(256), 0, stream, x, xb);
    for (int d = 0; d < 4; ++d)
        hipLaunchKernelGGL(k_cvtW, dim3(768), dim3(256), 0, stream, Wih[d], WihB + (size_t)d*NGE*NHE);
    for (int d = 0; d < 4; ++d)
        hipLaunchKernelGGL(k_cvtW, dim3(768), dim3(256), 0, stream, Whh[d], WhhB + (size_t)d*NGE*NHE);
    hipLaunchKernelGGL(k_gemm_M, dim3(48,16), dim3(256), 0, stream, dWih, linW, MbufB);
    hipLaunchKernelGGL(k_cvec, dim3(768), dim3(256), 0, stream, dWih, linb, dbih, cvec);
    hipLaunchKernelGGL(k_sx, dim3(4096), dim3(256), 0, stream, x, attnW, attnb, sx);
    hipLaunchKernelGGL(k_softprep2, dim3(64), dim3(256), 0, stream, sx, esb, Se);
    hipLaunchKernelGGL(k_xg_mfma, dim3(256,24,4), dim3(256), 0, stream,
                       xb, WihB, bih[0], bih[1], bih[2], bih[3], Xg);

    // phase 1: encoder recurrence (MFMA) -> hxh (bf16 history)
    {
        void* a[] = { (void*)&Xg, (void*)&WhhB,
                      (void*)&bhh[0], (void*)&bhh[1], (void*)&bhh[2], (void*)&bhh[3],
                      (void*)&hxh, (void*)&flagE };
        hipLaunchCooperativeKernel((void*)k_enc12, dim3(256), dim3(256), a, 0, stream);
    }

    // phase 2: z, mu/logvar outputs, attention statics, Gctx (MFMA)
    hipLaunchKernelGGL(k_zexp3, dim3(4096), dim3(256), 0, stream, hxh, eps, zbuf);
    hipLaunchKernelGGL(k_outT2, dim3(256,8), dim3(256), 0, stream, hxh, outMu, outLv);
    hipLaunchKernelGGL(k_cvtW, dim3(3072), dim3(256), 0, stream, dWhh, dWhhB);
    hipLaunchKernelGGL(k_cvtW, dim3(512), dim3(256), 0, stream, linW, linWB);
    hipLaunchKernelGGL(k_T2, dim3(1024), dim3(256), 0, stream, zbuf, esb, Tbuf);
    hipLaunchKernelGGL(k_ctx3, dim3(4096), dim3(256), 0, stream, zbuf, esb, Se, Tbuf, ctxT, ctxB);
    hipLaunchKernelGGL(k_gctx_mfma, dim3(256,48), dim3(256), 0, stream, ctxB, dWhhB, dbhh, Gctx);

    // phase 3: decoder recurrence (MFMA)
    {
        void* a[] = { (void*)&MbufB, (void*)&cvec, (void*)&dbih, (void*)&Gctx, (void*)&ctxT,
                      (void*)&Ht, (void*)&flagD };
        hipLaunchCooperativeKernel((void*)k_dec12, dim3(256), dim3(256), a, 0, stream);
    }

    // phase 4: output projection (MFMA)
    hipLaunchKernelGGL(k_rec_mfma, dim3(256,8), dim3(256), 0, stream, Ht, linWB, linb, outRec);
}

// Round 13
// 3905.979 us; speedup vs baseline: 1.1011x; 1.1011x over previous
//
#include <hip/hip_runtime.h>
#include <hip/hip_bf16.h>

typedef __hip_bfloat16 bf16;
typedef __attribute__((ext_vector_type(8))) short s8v;
typedef __attribute__((ext_vector_type(4))) float f32x4;
typedef __attribute__((ext_vector_type(4))) int int4v;

#define NB 64
#define NS 256
#define ND 512
#define NHE 512
#define NHD 1024
#define NGE 1536
#define NGD 3072

static __device__ __forceinline__ float sigmf(float x){ return 1.0f/(1.0f+__expf(-x)); }
static __device__ __forceinline__ float b2f(unsigned short u){ return __uint_as_float(((unsigned int)u) << 16); }
static __device__ __forceinline__ unsigned short f2bu(float f){
    bf16 v = __float2bfloat16(f);
    return *reinterpret_cast<unsigned short*>(&v);
}
static __device__ __forceinline__ s8v cast8(int4v v){
    union { int4v i; s8v s; } u; u.i = v; return u.s;
}
// LLC-coherent 2-byte store (bypass L1/L2 -> memory-side Infinity Cache)
static __device__ __forceinline__ void st2_llc(const void* p, unsigned int v){
    asm volatile("global_store_short %0, %1, off sc0 sc1"
                 :: "v"((unsigned long long)(uintptr_t)p), "v"(v) : "memory");
}

// 8x 16B LLC-coherent loads + drain.
#define LOADX8(BASEP, A0,A1,A2,A3,A4,A5,A6,A7)                                   \
    asm volatile(                                                                \
        "global_load_dwordx4 %0, %8, off sc0 sc1\n\t"                            \
        "global_load_dwordx4 %1, %8, off offset:64 sc0 sc1\n\t"                  \
        "global_load_dwordx4 %2, %8, off offset:128 sc0 sc1\n\t"                 \
        "global_load_dwordx4 %3, %8, off offset:192 sc0 sc1\n\t"                 \
        "global_load_dwordx4 %4, %8, off offset:256 sc0 sc1\n\t"                 \
        "global_load_dwordx4 %5, %8, off offset:320 sc0 sc1\n\t"                 \
        "global_load_dwordx4 %6, %8, off offset:384 sc0 sc1\n\t"                 \
        "global_load_dwordx4 %7, %8, off offset:448 sc0 sc1\n\t"                 \
        "s_waitcnt vmcnt(0)"                                                     \
        : "=&v"(A0),"=&v"(A1),"=&v"(A2),"=&v"(A3),                               \
          "=&v"(A4),"=&v"(A5),"=&v"(A6),"=&v"(A7)                                \
        : "v"((unsigned long long)(uintptr_t)(BASEP)) : "memory");               \
    __builtin_amdgcn_sched_barrier(0);

// ---- round-11 barriers: fence-free, single poll address per waiter ----
static __device__ __forceinline__ void groupbar_flat(unsigned int* base, int step, int nwg){
    __syncthreads();
    if (threadIdx.x == 0){
        unsigned int old = __hip_atomic_fetch_add(base, 1u, __ATOMIC_RELAXED, __HIP_MEMORY_SCOPE_AGENT);
        if ((int)old == step*nwg - 1)
            __hip_atomic_store(base + 32, (unsigned int)step, __ATOMIC_RELAXED, __HIP_MEMORY_SCOPE_AGENT);
        while ((int)__hip_atomic_load(base + 32, __ATOMIC_RELAXED, __HIP_MEMORY_SCOPE_AGENT) < step)
            __builtin_amdgcn_s_sleep(1);
    }
    __syncthreads();
}
// 8-leaf tree for 64-WG groups: leaf l at base[l*32], root at base[256], flag at base[288]
static __device__ __forceinline__ void groupbar_tree(unsigned int* base, int step, int leaf){
    __syncthreads();
    if (threadIdx.x == 0){
        unsigned int lo = __hip_atomic_fetch_add(base + leaf*32, 1u, __ATOMIC_RELAXED, __HIP_MEMORY_SCOPE_AGENT);
        if ((int)lo == step*8 - 1){
            unsigned int ro = __hip_atomic_fetch_add(base + 256, 1u, __ATOMIC_RELAXED, __HIP_MEMORY_SCOPE_AGENT);
            if ((int)ro == step*8 - 1)
                __hip_atomic_store(base + 288, (unsigned int)step, __ATOMIC_RELAXED, __HIP_MEMORY_SCOPE_AGENT);
        }
        while ((int)__hip_atomic_load(base + 288, __ATOMIC_RELAXED, __HIP_MEMORY_SCOPE_AGENT) < step)
            __builtin_amdgcn_s_sleep(1);
    }
    __syncthreads();
}

// ---------------- small prep kernels ----------------
__global__ __launch_bounds__(256) void k_sx(const float* __restrict__ x,
                                            const float* __restrict__ attnW,
                                            const float* __restrict__ attnb,
                                            float* __restrict__ sx){
    int row = blockIdx.x*4 + (threadIdx.x>>6);
    int lane = threadIdx.x & 63;
    float s = 0.f;
    for (int d = lane; d < ND; d += 64) s += x[(size_t)row*ND + d]*attnW[d];
    #pragma unroll
    for (int off = 32; off; off >>= 1) s += __shfl_down(s, off, 64);
    if (lane == 0) sx[row] = s + attnb[0];
}

__global__ __launch_bounds__(256) void k_cvec(const float* __restrict__ dWih,
                                              const float* __restrict__ linb,
                                              const float* __restrict__ dbih,
                                              float* __restrict__ cvec){
    int row = blockIdx.x*4 + (threadIdx.x>>6);
    int lane = threadIdx.x & 63;
    float s = 0.f;
    for (int d = lane; d < ND; d += 64) s += dWih[(size_t)row*ND + d]*linb[d];
    #pragma unroll
    for (int off = 32; off; off >>= 1) s += __shfl_down(s, off, 64);
    if (lane == 0) cvec[row] = s + dbih[row];
}

__global__ __launch_bounds__(256) void k_softprep2(const float* __restrict__ sx,
                                                   float* __restrict__ esb,
                                                   float* __restrict__ Se){
    int b = blockIdx.x, s = threadIdx.x;
    __shared__ float red[256];
    float v = sx[b*NS + s];
    red[s] = v; __syncthreads();
    for (int off = 128; off; off >>= 1){ if (s < off) red[s] = fmaxf(red[s], red[s+off]); __syncthreads(); }
    float mx = red[0]; __syncthreads();
    float ev = __expf(v - mx);
    esb[s*NB + b] = ev;
    red[s] = ev; __syncthreads();
    for (int off = 128; off; off >>= 1){ if (s < off) red[s] += red[s+off]; __syncthreads(); }
    if (s == 0) Se[b] = red[0];
}

__global__ __launch_bounds__(256) void k_cvtW(const float* __restrict__ W, bf16* __restrict__ o){
    size_t i = ((size_t)blockIdx.x*256 + threadIdx.x)*4;
    float4 v = *(const float4*)(W + i);
    o[i+0] = __float2bfloat16(v.x);
    o[i+1] = __float2bfloat16(v.y);
    o[i+2] = __float2bfloat16(v.z);
    o[i+3] = __float2bfloat16(v.w);
}

// z[t][h][b] from bf16 history hxh[dir][t][b][j]
__global__ __launch_bounds__(256) void k_zexp3(const bf16* __restrict__ hxh,
                                               const float* __restrict__ eps,
                                               bf16* __restrict__ z){
    int t  = blockIdx.x >> 4;
    int hb = blockIdx.x & 15;
    int dmu = hb >> 3;
    int jm0 = (hb & 7)*64;
    const unsigned short* hu = (const unsigned short*)hxh;
    __shared__ unsigned short zt[64][66];
    int tid = threadIdx.x;
    #pragma unroll
    for (int q = 0; q < 16; ++q){
        int bb = q*4 + (tid>>6);
        int hc = tid & 63;
        float mu = b2f(hu[(((size_t)(dmu*NS) + t)*64 + bb)*512 + jm0 + hc]);
        float lv = b2f(hu[(((size_t)((2+dmu)*NS) + t)*64 + bb)*512 + jm0 + hc]);
        float ep = eps[((size_t)bb*NS + t)*NHD + hb*64 + hc];
        zt[bb][hc] = f2bu(mu + ep*__expf(0.5f*lv));
    }
    __syncthreads();
    unsigned short* zu = (unsigned short*)z;
    int b = tid & 63;
    #pragma unroll
    for (int q = 0; q < 16; ++q){
        int hl = q*4 + (tid>>6);
        zu[((size_t)t*NHD + hb*64 + hl)*NB + b] = zt[b][hl];
    }
}

// mu/logvar outputs: coalesced copy from hxh[dir][t][b][j]
__global__ __launch_bounds__(256) void k_outT2(const bf16* __restrict__ hxh,
                                               float* __restrict__ outMu,
                                               float* __restrict__ outLv){
    int t  = blockIdx.x;
    int b0 = blockIdx.y*8;
    const unsigned short* hu = (const unsigned short*)hxh;
    int tid = threadIdx.x;
    #pragma unroll
    for (int q = 0; q < 16; ++q){
        int idx = q*256 + tid;
        int sel = idx >> 11;           // 0=mu 1=lv
        int rem = idx & 2047;
        int bb  = b0 + (rem >> 8);
        int h   = (rem & 255)*4;
        int dirn = (h >> 9) + sel*2;
        int j   = h & 511;
        ushort4 v = *(const ushort4*)(hu + (((size_t)(dirn*NS) + t)*64 + bb)*512 + j);
        float4 o;
        o.x = b2f(v.x); o.y = b2f(v.y); o.z = b2f(v.z); o.w = b2f(v.w);
        float* outp = sel ? outLv : outMu;
        *(float4*)(outp + ((size_t)bb*NS + t)*NHD + h) = o;
    }
}

__global__ __launch_bounds__(256) void k_T2(const bf16* __restrict__ z,
                                            const float* __restrict__ esb,
                                            float* __restrict__ T){
    int h = blockIdx.x;
    int b = threadIdx.x & 63;
    int sq = threadIdx.x >> 6;
    __shared__ float red[4][64];
    float acc = 0.f;
    #pragma unroll 8
    for (int s = sq*64; s < sq*64 + 64; ++s)
        acc += esb[s*NB + b]*__bfloat162float(z[((size_t)s*NHD + h)*NB + b]);
    red[sq][b] = acc; __syncthreads();
    if (sq == 0) T[h*NB + b] = red[0][b] + red[1][b] + red[2][b] + red[3][b];
}

__global__ __launch_bounds__(256) void k_ctx3(const bf16* __restrict__ z,
                                              const float* __restrict__ esb,
                                              const float* __restrict__ Se,
                                              const float* __restrict__ T,
                                              bf16* __restrict__ ctxT,
                                              bf16* __restrict__ ctxB){
    int i  = blockIdx.x >> 4;
    int hb = blockIdx.x & 15;
    int tid = threadIdx.x;
    int b  = tid & 63;
    __shared__ unsigned short tt[64][66];
    float ei  = esb[i*NB + b];
    float inv = 1.0f/(Se[b] - ei);
    #pragma unroll
    for (int q = 0; q < 16; ++q){
        int hl = q*4 + (tid>>6);
        int h = hb*64 + hl;
        float zv = __bfloat162float(z[((size_t)i*NHD + h)*NB + b]);
        float cv = (T[h*NB + b] - ei*zv)*inv;
        unsigned short u = f2bu(cv);
        ctxT[((size_t)i*NHD + h)*NB + b] = *reinterpret_cast<bf16*>(&u);
        tt[hl][b] = u;
    }
    __syncthreads();
    unsigned short* cb = (unsigned short*)ctxB;
    #pragma unroll
    for (int q = 0; q < 16; ++q){
        int bn = q*4 + (tid>>6);
        int hl = tid & 63;
        cb[((size_t)i*NB + bn)*NHD + hb*64 + hl] = tt[hl][bn];
    }
}

__global__ __launch_bounds__(256) void k_gemm_M(
    const float* __restrict__ dWih,
    const float* __restrict__ linW,
    bf16* __restrict__ M){
    int g0 = blockIdx.x*64;
    int h0 = blockIdx.y*64;
    __shared__ float As[64][36];
    __shared__ float Bs[32][68];
    int tid = threadIdx.x, tx = tid & 15, ty = tid >> 4;
    float acc[4][4] = {};
    for (int k0 = 0; k0 < ND; k0 += 32){
        #pragma unroll
        for (int m = 0; m < 8; ++m){
            int idx = m*256 + tid;
            int row = idx >> 5, kk = idx & 31;
            As[row][kk] = dWih[(size_t)(g0+row)*ND + k0 + kk];
            int k2 = idx >> 6, hh2 = idx & 63;
            Bs[k2][hh2] = linW[(size_t)(k0+k2)*NHD + h0 + hh2];
        }
        __syncthreads();
        for (int k = 0; k < 32; ++k){
            float a[4];
            #pragma unroll
            for (int i = 0; i < 4; ++i) a[i] = As[ty*4+i][k];
            float4 b4 = *(const float4*)&Bs[k][tx*4];
            #pragma unroll
            for (int i = 0; i < 4; ++i){
                acc[i][0] += a[i]*b4.x; acc[i][1] += a[i]*b4.y;
                acc[i][2] += a[i]*b4.z; acc[i][3] += a[i]*b4.w;
            }
        }
        __syncthreads();
    }
    #pragma unroll
    for (int i = 0; i < 4; ++i)
        #pragma unroll
        for (int j = 0; j < 4; ++j)
            M[(size_t)(g0+ty*4+i)*NHD + h0 + tx*4 + j] = __float2bfloat16(acc[i][j]);
}

// ---------------- MFMA prep GEMMs ----------------
__global__ __launch_bounds__(256, 2) void k_xg_mfma(
    const bf16* __restrict__ xb,     // [64][256][512]
    const bf16* __restrict__ WihB,   // [4][1536][512]
    const float* __restrict__ b0, const float* __restrict__ b1,
    const float* __restrict__ b2, const float* __restrict__ b3,
    bf16* __restrict__ Xg){
    int t = blockIdx.x, gblk = blockIdx.y, dir = blockIdx.z;
    const float* bih = dir==0?b0:dir==1?b1:dir==2?b2:b3;
    int tid = threadIdx.x;
    int lane = tid & 63;
    int w = __builtin_amdgcn_readfirstlane(tid >> 6);
    int ln = lane & 15, lk = lane >> 4;
    int g = gblk*64 + w*16 + ln;
    const unsigned short* Bp = (const unsigned short*)WihB + ((size_t)(dir*NGE + g))*512 + lk*8;
    s8v Bf[16];
    #pragma unroll
    for (int q = 0; q < 16; ++q) Bf[q] = *(const s8v*)(Bp + q*32);
    f32x4 C[4] = {};
    const unsigned short* xu = (const unsigned short*)xb;
    #pragma unroll
    for (int m = 0; m < 4; ++m){
        const unsigned short* Ap = xu + ((size_t)(m*16+ln)*NS + t)*ND + lk*8;
        #pragma unroll
        for (int q = 0; q < 16; ++q){
            s8v Af = *(const s8v*)(Ap + q*32);
            C[m] = __builtin_amdgcn_mfma_f32_16x16x32_bf16(Af, Bf[q], C[m], 0, 0, 0);
        }
    }
    float bi = bih[g];
    unsigned short* Op = (unsigned short*)Xg + ((size_t)(dir*NS + t)*NGE + g)*NB;
    #pragma unroll
    for (int m = 0; m < 4; ++m){
        ushort4 o;
        o.x = f2bu(C[m][0] + bi); o.y = f2bu(C[m][1] + bi);
        o.z = f2bu(C[m][2] + bi); o.w = f2bu(C[m][3] + bi);
        *(ushort4*)(Op + m*16 + lk*4) = o;
    }
}

__global__ __launch_bounds__(256, 2) void k_gctx_mfma(
    const bf16* __restrict__ ctxB,   // [256][64][1024]
    const bf16* __restrict__ dWhhB,  // [3072][1024]
    const float* __restrict__ bhh,
    bf16* __restrict__ Gctx){
    int i = blockIdx.x, gblk = blockIdx.y;
    int tid = threadIdx.x;
    int lane = tid & 63;
    int w = __builtin_amdgcn_readfirstlane(tid >> 6);
    int ln = lane & 15, lk = lane >> 4;
    int g = gblk*64 + w*16 + ln;
    f32x4 C[4] = {};
    const unsigned short* cu = (const unsigned short*)ctxB;
    const unsigned short* wu = (const unsigned short*)dWhhB;
    #pragma unroll
    for (int kc = 0; kc < 2; ++kc){
        const unsigned short* Bp = wu + (size_t)g*NHD + kc*512 + lk*8;
        s8v Bf[16];
        #pragma unroll
        for (int q = 0; q < 16; ++q) Bf[q] = *(const s8v*)(Bp + q*32);
        #pragma unroll
        for (int m = 0; m < 4; ++m){
            const unsigned short* Ap = cu + ((size_t)i*NB + m*16+ln)*NHD + kc*512 + lk*8;
            #pragma unroll
            for (int q = 0; q < 16; ++q){
                s8v Af = *(const s8v*)(Ap + q*32);
                C[m] = __builtin_amdgcn_mfma_f32_16x16x32_bf16(Af, Bf[q], C[m], 0, 0, 0);
            }
        }
    }
    float bi = bhh[g];
    unsigned short* Op = (unsigned short*)Gctx + ((size_t)i*NGD + g)*NB;
    #pragma unroll
    for (int m = 0; m < 4; ++m){
        ushort4 o;
        o.x = f2bu(C[m][0] + bi); o.y = f2bu(C[m][1] + bi);
        o.z = f2bu(C[m][2] + bi); o.w = f2bu(C[m][3] + bi);
        *(ushort4*)(Op + m*16 + lk*4) = o;
    }
}

__global__ __launch_bounds__(256, 2) void k_rec_mfma(
    const bf16* __restrict__ Ht,     // [256][64][1024]
    const bf16* __restrict__ linWB,  // [512][1024]
    const float* __restrict__ linb,
    float* __restrict__ outRec){
    int i = blockIdx.x, dblk = blockIdx.y;
    int tid = threadIdx.x;
    int lane = tid & 63;
    int w = __builtin_amdgcn_readfirstlane(tid >> 6);
    int ln = lane & 15, lk = lane >> 4;
    int d = dblk*64 + w*16 + ln;
    f32x4 C[4] = {};
    const unsigned short* hu = (const unsigned short*)Ht;
    const unsigned short* wu = (const unsigned short*)linWB;
    #pragma unroll
    for (int kc = 0; kc < 2; ++kc){
        const unsigned short* Bp = wu + (size_t)d*NHD + kc*512 + lk*8;
        s8v Bf[16];
        #pragma unroll
        for (int q = 0; q < 16; ++q) Bf[q] = *(const s8v*)(Bp + q*32);
        #pragma unroll
        for (int m = 0; m < 4; ++m){
            const unsigned short* Ap = hu + ((size_t)i*NB + m*16+ln)*NHD + kc*512 + lk*8;
            #pragma unroll
            for (int q = 0; q < 16; ++q){
                s8v Af = *(const s8v*)(Ap + q*32);
                C[m] = __builtin_amdgcn_mfma_f32_16x16x32_bf16(Af, Bf[q], C[m], 0, 0, 0);
            }
        }
    }
    float lb = linb[d];
    #pragma unroll
    for (int m = 0; m < 4; ++m)
        #pragma unroll
        for (int r = 0; r < 4; ++r){
            int b = m*16 + lk*4 + r;
            outRec[((size_t)b*NS + i)*ND + d] = C[m][r] + lb;
        }
}

// ---------------- MFMA recurrence kernels (tree barrier, LLC exchange, bf16 history) ----------------
__global__ __launch_bounds__(256, 1) void k_enc13(
    const bf16* __restrict__ Xg,
    const bf16* __restrict__ WB,     // [4][1536][512] bf16
    const float* __restrict__ b0, const float* __restrict__ b1,
    const float* __restrict__ b2, const float* __restrict__ b3,
    bf16* __restrict__ hxh,          // [4][256][64][512] bf16 (history == exchange)
    unsigned int* __restrict__ bar){
    int wg  = blockIdx.x;
    int grp = wg & 15;
    int wl  = wg >> 4;
    int dir = grp >> 2;
    int bq  = grp & 3;
    int tid = threadIdx.x;
    int lane = tid & 63;
    int wid = __builtin_amdgcn_readfirstlane(tid >> 6);
    int jl = wid & 1, kh = wid >> 1;
    int jt = wl*2 + jl;
    int ln = lane & 15, lk = lane >> 4;
    int j  = jt*16 + ln;
    int b0v = bq*16 + lk*4;
    const float* bhh = dir==0?b0:dir==1?b1:dir==2?b2:b3;
    const unsigned short* WBu = (const unsigned short*)WB;
    s8v Bf[3][8];
    #pragma unroll
    for (int g = 0; g < 3; ++g)
        #pragma unroll
        for (int q = 0; q < 8; ++q)
            Bf[g][q] = *(const s8v*)(WBu + ((size_t)(dir*NGE + g*512 + j))*512 + (kh*8+q)*32 + lk*8);
    float br=0.f, bz=0.f, bn=0.f;
    if (kh == 0){ br = bhh[j]; bz = bhh[j+512]; bn = bhh[j+1024]; }
    float hp0=0.f, hp1=0.f, hp2=0.f, hp3=0.f;
    __shared__ float red[2][3][64][4];
    unsigned int* gb = bar + grp*64;
    const unsigned short* Xgu = (const unsigned short*)Xg;
    const unsigned short* hu = (const unsigned short*)hxh;
    ushort4 xr, xz, xn;
    if (kh == 0){
        int t0 = (dir & 1) ? 255 : 0;
        size_t xb_ = (size_t)(dir*NS + t0)*NGE;
        xr = *(const ushort4*)(Xgu + (xb_ + j)*NB + b0v);
        xz = *(const ushort4*)(Xgu + (xb_ + j + 512)*NB + b0v);
        xn = *(const ushort4*)(Xgu + (xb_ + j + 1024)*NB + b0v);
    }
    for (int t = 0; t < NS; ++t){
        int tcur = (dir & 1) ? (255 - t) : t;
        f32x4 C0 = {0.f,0.f,0.f,0.f}, C1 = {0.f,0.f,0.f,0.f}, C2 = {0.f,0.f,0.f,0.f};
        if (t > 0){
            int tprev = (dir & 1) ? (256 - t) : (t - 1);
            const unsigned short* hxr = hu
                + (((size_t)(dir*NS + tprev))*64 + bq*16 + ln)*512 + kh*256 + lk*8;
            int4v a0,a1,a2,a3,a4,a5,a6,a7;
            LOADX8(hxr, a0,a1,a2,a3,a4,a5,a6,a7)
            s8v Af;
            #define MF3(AV) Af = cast8(AV); \
                C0 = __builtin_amdgcn_mfma_f32_16x16x32_bf16(Af, Bf[0][__q], C0, 0, 0, 0); \
                C1 = __builtin_amdgcn_mfma_f32_16x16x32_bf16(Af, Bf[1][__q], C1, 0, 0, 0); \
                C2 = __builtin_amdgcn_mfma_f32_16x16x32_bf16(Af, Bf[2][__q], C2, 0, 0, 0);
            { enum {__q=0}; MF3(a0) } { enum {__q=1}; MF3(a1) }
            { enum {__q=2}; MF3(a2) } { enum {__q=3}; MF3(a3) }
            { enum {__q=4}; MF3(a4) } { enum {__q=5}; MF3(a5) }
            { enum {__q=6}; MF3(a6) } { enum {__q=7}; MF3(a7) }
            #undef MF3
        }
        if (kh == 1){
            *(f32x4*)&red[jl][0][lane][0] = C0;
            *(f32x4*)&red[jl][1][lane][0] = C1;
            *(f32x4*)&red[jl][2][lane][0] = C2;
        }
        __syncthreads();
        if (kh == 0){
            C0 += *(const f32x4*)&red[jl][0][lane][0];
            C1 += *(const f32x4*)&red[jl][1][lane][0];
            C2 += *(const f32x4*)&red[jl][2][lane][0];
            {
                float r_ = sigmf(b2f(xr.x) + C0[0] + br);
                float z_ = sigmf(b2f(xz.x) + C1[0] + bz);
                float n_ = tanhf(b2f(xn.x) + r_*(C2[0] + bn));
                hp0 = (1.f - z_)*n_ + z_*hp0;
            }
            {
                float r_ = sigmf(b2f(xr.y) + C0[1] + br);
                float z_ = sigmf(b2f(xz.y) + C1[1] + bz);
                float n_ = tanhf(b2f(xn.y) + r_*(C2[1] + bn));
                hp1 = (1.f - z_)*n_ + z_*hp1;
            }
            {
                float r_ = sigmf(b2f(xr.z) + C0[2] + br);
                float z_ = sigmf(b2f(xz.z) + C1[2] + bz);
                float n_ = tanhf(b2f(xn.z) + r_*(C2[2] + bn));
                hp2 = (1.f - z_)*n_ + z_*hp2;
            }
            {
                float r_ = sigmf(b2f(xr.w) + C0[3] + br);
                float z_ = sigmf(b2f(xz.w) + C1[3] + bz);
                float n_ = tanhf(b2f(xn.w) + r_*(C2[3] + bn));
                hp3 = (1.f - z_)*n_ + z_*hp3;
            }
            const unsigned short* hw = hu + ((size_t)(dir*NS + tcur))*64*512;
            st2_llc(hw + (size_t)(b0v+0)*512 + j, (unsigned int)f2bu(hp0));
            st2_llc(hw + (size_t)(b0v+1)*512 + j, (unsigned int)f2bu(hp1));
            st2_llc(hw + (size_t)(b0v+2)*512 + j, (unsigned int)f2bu(hp2));
            st2_llc(hw + (size_t)(b0v+3)*512 + j, (unsigned int)f2bu(hp3));
            if (t < NS-1){   // prefetch next step's read-only gates (cached loads)
                int tn = (dir & 1) ? (254 - t) : (t + 1);
                size_t xb_ = (size_t)(dir*NS + tn)*NGE;
                xr = *(const ushort4*)(Xgu + (xb_ + j)*NB + b0v);
                xz = *(const ushort4*)(Xgu + (xb_ + j + 512)*NB + b0v);
                xn = *(const ushort4*)(Xgu + (xb_ + j + 1024)*NB + b0v);
            }
        }
        if (t < NS-1) groupbar_flat(gb, t+1, 16);
    }
}

__global__ __launch_bounds__(256, 1) void k_dec13(
    const bf16* __restrict__ MB,     // [3072][1024] bf16
    const float* __restrict__ cvec,
    const float* __restrict__ dbih,
    const bf16* __restrict__ Gctx,
    const bf16* __restrict__ ctxT,
    bf16* __restrict__ Ht,           // [256][64][1024] bf16 history (LLC-coherent)
    unsigned int* __restrict__ bar){
    int wg  = blockIdx.x;
    int grp = wg & 3;
    int jt  = wg >> 2;
    int tid = threadIdx.x;
    int lane = tid & 63;
    int wid = __builtin_amdgcn_readfirstlane(tid >> 6);
    int ln = lane & 15, lk = lane >> 4;
    int j  = jt*16 + ln;
    int b0v = grp*16 + lk*4;
    const unsigned short* MBu = (const unsigned short*)MB;
    s8v Bf[3][8];
    #pragma unroll
    for (int g = 0; g < 3; ++g)
        #pragma unroll
        for (int q = 0; q < 8; ++q)
            Bf[g][q] = *(const s8v*)(MBu + ((size_t)(g*NHD + j))*NHD + wid*256 + q*32 + lk*8);
    float c0=0.f,c1=0.f,c2=0.f,d0v=0.f,d1v=0.f,d2v=0.f;
    if (wid == 0){
        c0 = cvec[j]; c1 = cvec[j+NHD]; c2 = cvec[j+2*NHD];
        d0v = dbih[j]; d1v = dbih[j+NHD]; d2v = dbih[j+2*NHD];
    }
    __shared__ float red[3][3][64][4];
    unsigned int* gb = bar + grp*512;
    int leaf = jt & 7;
    const unsigned short* Gu = (const unsigned short*)Gctx;
    const unsigned short* Cu = (const unsigned short*)ctxT;
    const unsigned short* hu = (const unsigned short*)Ht;
    ushort4 gr, gz, gn, cx;
    if (wid == 0){
        gr = *(const ushort4*)(Gu + (size_t)j*NB + b0v);
        gz = *(const ushort4*)(Gu + (size_t)(j+NHD)*NB + b0v);
        gn = *(const ushort4*)(Gu + (size_t)(j+2*NHD)*NB + b0v);
        cx = *(const ushort4*)(Cu + (size_t)j*NB + b0v);
    }
    for (int i = 0; i < NS; ++i){
        f32x4 C0 = {0.f,0.f,0.f,0.f}, C1 = {0.f,0.f,0.f,0.f}, C2 = {0.f,0.f,0.f,0.f};
        if (i > 0){
            const unsigned short* hxr = hu
                + ((size_t)(i-1)*NB + grp*16 + ln)*NHD + wid*256 + lk*8;
            int4v a0,a1,a2,a3,a4,a5,a6,a7;
            LOADX8(hxr, a0,a1,a2,a3,a4,a5,a6,a7)
            s8v Af;
            #define MF3(AV) Af = cast8(AV); \
                C0 = __builtin_amdgcn_mfma_f32_16x16x32_bf16(Af, Bf[0][__q], C0, 0, 0, 0); \
                C1 = __builtin_amdgcn_mfma_f32_16x16x32_bf16(Af, Bf[1][__q], C1, 0, 0, 0); \
                C2 = __builtin_amdgcn_mfma_f32_16x16x32_bf16(Af, Bf[2][__q], C2, 0, 0, 0);
            { enum {__q=0}; MF3(a0) } { enum {__q=1}; MF3(a1) }
            { enum {__q=2}; MF3(a2) } { enum {__q=3}; MF3(a3) }
            { enum {__q=4}; MF3(a4) } { enum {__q=5}; MF3(a5) }
            { enum {__q=6}; MF3(a6) } { enum {__q=7}; MF3(a7) }
            #undef MF3
        }
        if (wid != 0){
            *(f32x4*)&red[wid-1][0][lane][0] = C0;
            *(f32x4*)&red[wid-1][1][lane][0] = C1;
            *(f32x4*)&red[wid-1][2][lane][0] = C2;
        }
        __syncthreads();
        if (wid == 0){
            #pragma unroll
            for (int w = 0; w < 3; ++w){
                C0 += *(const f32x4*)&red[w][0][lane][0];
                C1 += *(const f32x4*)&red[w][1][lane][0];
                C2 += *(const f32x4*)&red[w][2][lane][0];
            }
            f32x4 ho;
            {
                float g0v = (i==0) ? d0v : C0[0] + c0;
                float g1v = (i==0) ? d1v : C1[0] + c1;
                float g2v = (i==0) ? d2v : C2[0] + c2;
                float r_ = sigmf(g0v + b2f(gr.x));
                float z_ = sigmf(g1v + b2f(gz.x));
                float n_ = tanhf(g2v + r_*b2f(gn.x));
                ho[0] = (1.f - z_)*n_ + z_*b2f(cx.x);
            }
            {
                float g0v = (i==0) ? d0v : C0[1] + c0;
                float g1v = (i==0) ? d1v : C1[1] + c1;
                float g2v = (i==0) ? d2v : C2[1] + c2;
                float r_ = sigmf(g0v + b2f(gr.y));
                float z_ = sigmf(g1v + b2f(gz.y));
                float n_ = tanhf(g2v + r_*b2f(gn.y));
                ho[1] = (1.f - z_)*n_ + z_*b2f(cx.y);
            }
            {
                float g0v = (i==0) ? d0v : C0[2] + c0;
                float g1v = (i==0) ? d1v : C1[2] + c1;
                float g2v = (i==0) ? d2v : C2[2] + c2;
                float r_ = sigmf(g0v + b2f(gr.z));
                float z_ = sigmf(g1v + b2f(gz.z));
                float n_ = tanhf(g2v + r_*b2f(gn.z));
                ho[2] = (1.f - z_)*n_ + z_*b2f(cx.z);
            }
            {
                float g0v = (i==0) ? d0v : C0[3] + c0;
                float g1v = (i==0) ? d1v : C1[3] + c1;
                float g2v = (i==0) ? d2v : C2[3] + c2;
                float r_ = sigmf(g0v + b2f(gr.w));
                float z_ = sigmf(g1v + b2f(gz.w));
                float n_ = tanhf(g2v + r_*b2f(gn.w));
                ho[3] = (1.f - z_)*n_ + z_*b2f(cx.w);
            }
            const unsigned short* hw = hu + (size_t)i*NB*NHD;
            st2_llc(hw + (size_t)(b0v+0)*NHD + j, (unsigned int)f2bu(ho[0]));
            st2_llc(hw + (size_t)(b0v+1)*NHD + j, (unsigned int)f2bu(ho[1]));
            st2_llc(hw + (size_t)(b0v+2)*NHD + j, (unsigned int)f2bu(ho[2]));
            st2_llc(hw + (size_t)(b0v+3)*NHD + j, (unsigned int)f2bu(ho[3]));
            if (i < NS-1){   // prefetch next step's read-only operands (cached)
                size_t gbx = (size_t)(i+1)*NGD*NB;
                gr = *(const ushort4*)(Gu + gbx + (size_t)j*NB + b0v);
                gz = *(const ushort4*)(Gu + gbx + (size_t)(j+NHD)*NB + b0v);
                gn = *(const ushort4*)(Gu + gbx + (size_t)(j+2*NHD)*NB + b0v);
                cx = *(const ushort4*)(Cu + ((size_t)(i+1)*NHD + j)*NB + b0v);
            }
        }
        if (i < NS-1) groupbar_tree(gb, i+1, leaf);
    }
}

// ---------------- host launcher ----------------
extern "C" void kernel_launch(void* const* d_in, const int* in_sizes, int n_in,
                              void* d_out, int out_size, void* d_ws, size_t ws_size,
                              hipStream_t stream){
    const float* x   = (const float*)d_in[0];
    const float* eps = (const float*)d_in[1];
    const float* Wih[4]; const float* Whh[4]; const float* bih[4]; const float* bhh[4];
    for (int d = 0; d < 4; ++d){
        Wih[d] = (const float*)d_in[2 + 4*d];
        Whh[d] = (const float*)d_in[3 + 4*d];
        bih[d] = (const float*)d_in[4 + 4*d];
        bhh[d] = (const float*)d_in[5 + 4*d];
    }
    const float* dWih  = (const float*)d_in[18];
    const float* dWhh  = (const float*)d_in[19];
    const float* dbih  = (const float*)d_in[20];
    const float* dbhh  = (const float*)d_in[21];
    const float* attnW = (const float*)d_in[22];
    const float* attnb = (const float*)d_in[23];
    const float* linW  = (const float*)d_in[24];
    const float* linb  = (const float*)d_in[25];

    float* out    = (float*)d_out;
    float* outRec = out;
    float* outMu  = out + 8388608;
    float* outLv  = out + 25165824;

    char* ws = (char*)d_ws;
    bf16*  Xg    = (bf16*)(ws + 0);              // ph0-1: 201326592
    bf16*  Gctx  = (bf16*)(ws + 0);              // ph2-3: 100663296
    bf16*  ctxB  = (bf16*)(ws + 100663296);      // ph2:   33554432 (inside dead Xg)
    bf16*  hxh   = (bf16*)(ws + 201326592);      // ph1-2: 67108864
    bf16*  zbuf  = (bf16*)(ws + 268435456);      // ph2:   33554432
    bf16*  ctxT  = (bf16*)(ws + 301989888);      // ph2-3: 33554432
    bf16*  Ht    = (bf16*)(ws + 335544320);      // ph3-4: 33554432
    bf16*  xb    = (bf16*)(ws + 369098752);      // ph0:   16777216
    bf16*  WihB  = (bf16*)(ws + 385875968);      // ph0:   6291456
    bf16*  WhhB  = (bf16*)(ws + 392167424);      // ph0-1: 6291456
    bf16*  MbufB = (bf16*)(ws + 398458880);      // 6291456
    bf16*  dWhhB = (bf16*)(ws + 404750336);      // ph2:   6291456
    bf16*  linWB = (bf16*)(ws + 411041792);      // 1048576
    float* sx    = (float*)(ws + 412090368);     // 65536
    float* esb   = (float*)(ws + 412155904);     // 65536
    float* Se    = (float*)(ws + 412221440);     // 4096
    float* Tbuf  = (float*)(ws + 412225536);     // 262144
    float* cvec  = (float*)(ws + 412487680);     // 12288
    unsigned int* barE = (unsigned int*)(ws + 412499968);  // 16384 (16 groups x 256B)
    unsigned int* barD = (unsigned int*)(ws + 412516352);  // 16384 (4 groups x 2KB tree)

    hipMemsetAsync(ws + 412499968, 0, 32768, stream);

    // phase 0: conversions + statics + Xg (MFMA)
    hipLaunchKernelGGL(k_cvtW, dim3(8192), dim3(256), 0, stream, x, xb);
    for (int d = 0; d < 4; ++d)
        hipLaunchKernelGGL(k_cvtW, dim3(768), dim3(256), 0, stream, Wih[d], WihB + (size_t)d*NGE*NHE);
    for (int d = 0; d < 4; ++d)
        hipLaunchKernelGGL(k_cvtW, dim3(768), dim3(256), 0, stream, Whh[d], WhhB + (size_t)d*NGE*NHE);
    hipLaunchKernelGGL(k_gemm_M, dim3(48,16), dim3(256), 0, stream, dWih, linW, MbufB);
    hipLaunchKernelGGL(k_cvec, dim3(768), dim3(256), 0, stream, dWih, linb, dbih, cvec);
    hipLaunchKernelGGL(k_sx, dim3(4096), dim3(256), 0, stream, x, attnW, attnb, sx);
    hipLaunchKernelGGL(k_softprep2, dim3(64), dim3(256), 0, stream, sx, esb, Se);
    hipLaunchKernelGGL(k_xg_mfma, dim3(256,24,4), dim3(256), 0, stream,
                       xb, WihB, bih[0], bih[1], bih[2], bih[3], Xg);

    // phase 1: encoder recurrence (MFMA) -> hxh (bf16 history)
    {
        void* a[] = { (void*)&Xg, (void*)&WhhB,
                      (void*)&bhh[0], (void*)&bhh[1], (void*)&bhh[2], (void*)&bhh[3],
                      (void*)&hxh, (void*)&barE };
        hipLaunchCooperativeKernel((void*)k_enc13, dim3(256), dim3(256), a, 0, stream);
    }

    // phase 2: z, mu/logvar outputs, attention statics, Gctx (MFMA)
    hipLaunchKernelGGL(k_zexp3, dim3(4096), dim3(256), 0, stream, hxh, eps, zbuf);
    hipLaunchKernelGGL(k_outT2, dim3(256,8), dim3(256), 0, stream, hxh, outMu, outLv);
    hipLaunchKernelGGL(k_cvtW, dim3(3072), dim3(256), 0, stream, dWhh, dWhhB);
    hipLaunchKernelGGL(k_cvtW, dim3(512), dim3(256), 0, stream, linW, linWB);
    hipLaunchKernelGGL(k_T2, dim3(1024), dim3(256), 0, stream, zbuf, esb, Tbuf);
    hipLaunchKernelGGL(k_ctx3, dim3(4096), dim3(256), 0, stream, zbuf, esb, Se, Tbuf, ctxT, ctxB);
    hipLaunchKernelGGL(k_gctx_mfma, dim3(256,48), dim3(256), 0, stream, ctxB, dWhhB, dbhh, Gctx);

    // phase 3: decoder recurrence (MFMA)
    {
        void* a[] = { (void*)&MbufB, (void*)&cvec, (void*)&dbih, (void*)&Gctx, (void*)&ctxT,
                      (void*)&Ht, (void*)&barD };
        hipLaunchCooperativeKernel((void*)k_dec13, dim3(256), dim3(256), a, 0, stream);
    }

    // phase 4: output projection (MFMA)
    hipLaunchKernelGGL(k_rec_mfma, dim3(256,8), dim3(256), 0, stream, Ht, linWB, linb, outRec);
}

// Round 14
// 3658.471 us; speedup vs baseline: 1.1755x; 1.0677x over previous
//
#include <hip/hip_runtime.h>
#include <hip/hip_bf16.h>

typedef __hip_bfloat16 bf16;
typedef __attribute__((ext_vector_type(8))) short s8v;
typedef __attribute__((ext_vector_type(4))) float f32x4;
typedef __attribute__((ext_vector_type(4))) int int4v;

#define NB 64
#define NS 256
#define ND 512
#define NHE 512
#define NHD 1024
#define NGE 1536
#define NGD 3072

static __device__ __forceinline__ float sigmf(float x){ return 1.0f/(1.0f+__expf(-x)); }
static __device__ __forceinline__ float b2f(unsigned short u){ return __uint_as_float(((unsigned int)u) << 16); }
static __device__ __forceinline__ unsigned short f2bu(float f){
    bf16 v = __float2bfloat16(f);
    return *reinterpret_cast<unsigned short*>(&v);
}
static __device__ __forceinline__ s8v cast8(int4v v){
    union { int4v i; s8v s; } u; u.i = v; return u.s;
}
// LLC-coherent 2-byte store (bypass L1/L2 -> memory-side Infinity Cache)
static __device__ __forceinline__ void st2_llc(const void* p, unsigned int v){
    asm volatile("global_store_short %0, %1, off sc0 sc1"
                 :: "v"((unsigned long long)(uintptr_t)p), "v"(v) : "memory");
}

// 8x 16B LLC-coherent loads + drain.
#define LOADX8(BASEP, A0,A1,A2,A3,A4,A5,A6,A7)                                   \
    asm volatile(                                                                \
        "global_load_dwordx4 %0, %8, off sc0 sc1\n\t"                            \
        "global_load_dwordx4 %1, %8, off offset:64 sc0 sc1\n\t"                  \
        "global_load_dwordx4 %2, %8, off offset:128 sc0 sc1\n\t"                 \
        "global_load_dwordx4 %3, %8, off offset:192 sc0 sc1\n\t"                 \
        "global_load_dwordx4 %4, %8, off offset:256 sc0 sc1\n\t"                 \
        "global_load_dwordx4 %5, %8, off offset:320 sc0 sc1\n\t"                 \
        "global_load_dwordx4 %6, %8, off offset:384 sc0 sc1\n\t"                 \
        "global_load_dwordx4 %7, %8, off offset:448 sc0 sc1\n\t"                 \
        "s_waitcnt vmcnt(0)"                                                     \
        : "=&v"(A0),"=&v"(A1),"=&v"(A2),"=&v"(A3),                               \
          "=&v"(A4),"=&v"(A5),"=&v"(A6),"=&v"(A7)                                \
        : "v"((unsigned long long)(uintptr_t)(BASEP)) : "memory");               \
    __builtin_amdgcn_sched_barrier(0);

// ---- barriers v6: waiters poll the monotonic arrival counter directly.
// counter >= step*nwg  <=>  all nwg WGs arrived for this step (each WG arrives
// exactly once per step and cannot arrive for step t+1 before passing step t).
static __device__ __forceinline__ void groupbar_flat(unsigned int* base, int step, int nwg){
    __syncthreads();
    if (threadIdx.x == 0){
        __hip_atomic_fetch_add(base, 1u, __ATOMIC_RELAXED, __HIP_MEMORY_SCOPE_AGENT);
        while ((int)__hip_atomic_load(base, __ATOMIC_RELAXED, __HIP_MEMORY_SCOPE_AGENT) < step*nwg)
            __builtin_amdgcn_s_sleep(1);
    }
    __syncthreads();
}
// 8-leaf tree for 64-WG groups: leaf l at base[l*32], root at base[256].
static __device__ __forceinline__ void groupbar_tree(unsigned int* base, int step, int leaf){
    __syncthreads();
    if (threadIdx.x == 0){
        unsigned int lo = __hip_atomic_fetch_add(base + leaf*32, 1u, __ATOMIC_RELAXED, __HIP_MEMORY_SCOPE_AGENT);
        if ((int)lo == step*8 - 1)
            __hip_atomic_fetch_add(base + 256, 1u, __ATOMIC_RELAXED, __HIP_MEMORY_SCOPE_AGENT);
        while ((int)__hip_atomic_load(base + 256, __ATOMIC_RELAXED, __HIP_MEMORY_SCOPE_AGENT) < step*8)
            __builtin_amdgcn_s_sleep(1);
    }
    __syncthreads();
}

// ---------------- small prep kernels ----------------
__global__ __launch_bounds__(256) void k_sx(const float* __restrict__ x,
                                            const float* __restrict__ attnW,
                                            const float* __restrict__ attnb,
                                            float* __restrict__ sx){
    int row = blockIdx.x*4 + (threadIdx.x>>6);
    int lane = threadIdx.x & 63;
    float s = 0.f;
    for (int d = lane; d < ND; d += 64) s += x[(size_t)row*ND + d]*attnW[d];
    #pragma unroll
    for (int off = 32; off; off >>= 1) s += __shfl_down(s, off, 64);
    if (lane == 0) sx[row] = s + attnb[0];
}

__global__ __launch_bounds__(256) void k_cvec(const float* __restrict__ dWih,
                                              const float* __restrict__ linb,
                                              const float* __restrict__ dbih,
                                              float* __restrict__ cvec){
    int row = blockIdx.x*4 + (threadIdx.x>>6);
    int lane = threadIdx.x & 63;
    float s = 0.f;
    for (int d = lane; d < ND; d += 64) s += dWih[(size_t)row*ND + d]*linb[d];
    #pragma unroll
    for (int off = 32; off; off >>= 1) s += __shfl_down(s, off, 64);
    if (lane == 0) cvec[row] = s + dbih[row];
}

__global__ __launch_bounds__(256) void k_softprep2(const float* __restrict__ sx,
                                                   float* __restrict__ esb,
                                                   float* __restrict__ Se){
    int b = blockIdx.x, s = threadIdx.x;
    __shared__ float red[256];
    float v = sx[b*NS + s];
    red[s] = v; __syncthreads();
    for (int off = 128; off; off >>= 1){ if (s < off) red[s] = fmaxf(red[s], red[s+off]); __syncthreads(); }
    float mx = red[0]; __syncthreads();
    float ev = __expf(v - mx);
    esb[s*NB + b] = ev;
    red[s] = ev; __syncthreads();
    for (int off = 128; off; off >>= 1){ if (s < off) red[s] += red[s+off]; __syncthreads(); }
    if (s == 0) Se[b] = red[0];
}

__global__ __launch_bounds__(256) void k_cvtW(const float* __restrict__ W, bf16* __restrict__ o){
    size_t i = ((size_t)blockIdx.x*256 + threadIdx.x)*4;
    float4 v = *(const float4*)(W + i);
    o[i+0] = __float2bfloat16(v.x);
    o[i+1] = __float2bfloat16(v.y);
    o[i+2] = __float2bfloat16(v.z);
    o[i+3] = __float2bfloat16(v.w);
}

// 4 source matrices -> one packed bf16 buffer (y selects source)
__global__ __launch_bounds__(256) void k_cvtW4(
    const float* __restrict__ p0, const float* __restrict__ p1,
    const float* __restrict__ p2, const float* __restrict__ p3,
    bf16* __restrict__ o){
    int y = blockIdx.y;
    const float* W = (y==0)?p0:(y==1)?p1:(y==2)?p2:p3;
    size_t i = ((size_t)blockIdx.x*256 + threadIdx.x)*4;
    float4 v = *(const float4*)(W + i);
    bf16* d = o + (size_t)y*NGE*NHE;
    d[i+0] = __float2bfloat16(v.x);
    d[i+1] = __float2bfloat16(v.y);
    d[i+2] = __float2bfloat16(v.z);
    d[i+3] = __float2bfloat16(v.w);
}

// z[t][h][b] from bf16 history hxh[dir][t][b][j]
__global__ __launch_bounds__(256) void k_zexp3(const bf16* __restrict__ hxh,
                                               const float* __restrict__ eps,
                                               bf16* __restrict__ z){
    int t  = blockIdx.x >> 4;
    int hb = blockIdx.x & 15;
    int dmu = hb >> 3;
    int jm0 = (hb & 7)*64;
    const unsigned short* hu = (const unsigned short*)hxh;
    __shared__ unsigned short zt[64][66];
    int tid = threadIdx.x;
    #pragma unroll
    for (int q = 0; q < 16; ++q){
        int bb = q*4 + (tid>>6);
        int hc = tid & 63;
        float mu = b2f(hu[(((size_t)(dmu*NS) + t)*64 + bb)*512 + jm0 + hc]);
        float lv = b2f(hu[(((size_t)((2+dmu)*NS) + t)*64 + bb)*512 + jm0 + hc]);
        float ep = eps[((size_t)bb*NS + t)*NHD + hb*64 + hc];
        zt[bb][hc] = f2bu(mu + ep*__expf(0.5f*lv));
    }
    __syncthreads();
    unsigned short* zu = (unsigned short*)z;
    int b = tid & 63;
    #pragma unroll
    for (int q = 0; q < 16; ++q){
        int hl = q*4 + (tid>>6);
        zu[((size_t)t*NHD + hb*64 + hl)*NB + b] = zt[b][hl];
    }
}

// mu/logvar outputs: coalesced copy from hxh[dir][t][b][j]
__global__ __launch_bounds__(256) void k_outT2(const bf16* __restrict__ hxh,
                                               float* __restrict__ outMu,
                                               float* __restrict__ outLv){
    int t  = blockIdx.x;
    int b0 = blockIdx.y*8;
    const unsigned short* hu = (const unsigned short*)hxh;
    int tid = threadIdx.x;
    #pragma unroll
    for (int q = 0; q < 16; ++q){
        int idx = q*256 + tid;
        int sel = idx >> 11;           // 0=mu 1=lv
        int rem = idx & 2047;
        int bb  = b0 + (rem >> 8);
        int h   = (rem & 255)*4;
        int dirn = (h >> 9) + sel*2;
        int j   = h & 511;
        ushort4 v = *(const ushort4*)(hu + (((size_t)(dirn*NS) + t)*64 + bb)*512 + j);
        float4 o;
        o.x = b2f(v.x); o.y = b2f(v.y); o.z = b2f(v.z); o.w = b2f(v.w);
        float* outp = sel ? outLv : outMu;
        *(float4*)(outp + ((size_t)bb*NS + t)*NHD + h) = o;
    }
}

__global__ __launch_bounds__(256) void k_T2(const bf16* __restrict__ z,
                                            const float* __restrict__ esb,
                                            float* __restrict__ T){
    int h = blockIdx.x;
    int b = threadIdx.x & 63;
    int sq = threadIdx.x >> 6;
    __shared__ float red[4][64];
    float acc = 0.f;
    #pragma unroll 8
    for (int s = sq*64; s < sq*64 + 64; ++s)
        acc += esb[s*NB + b]*__bfloat162float(z[((size_t)s*NHD + h)*NB + b]);
    red[sq][b] = acc; __syncthreads();
    if (sq == 0) T[h*NB + b] = red[0][b] + red[1][b] + red[2][b] + red[3][b];
}

__global__ __launch_bounds__(256) void k_ctx3(const bf16* __restrict__ z,
                                              const float* __restrict__ esb,
                                              const float* __restrict__ Se,
                                              const float* __restrict__ T,
                                              bf16* __restrict__ ctxT,
                                              bf16* __restrict__ ctxB){
    int i  = blockIdx.x >> 4;
    int hb = blockIdx.x & 15;
    int tid = threadIdx.x;
    int b  = tid & 63;
    __shared__ unsigned short tt[64][66];
    float ei  = esb[i*NB + b];
    float inv = 1.0f/(Se[b] - ei);
    #pragma unroll
    for (int q = 0; q < 16; ++q){
        int hl = q*4 + (tid>>6);
        int h = hb*64 + hl;
        float zv = __bfloat162float(z[((size_t)i*NHD + h)*NB + b]);
        float cv = (T[h*NB + b] - ei*zv)*inv;
        unsigned short u = f2bu(cv);
        ctxT[((size_t)i*NHD + h)*NB + b] = *reinterpret_cast<bf16*>(&u);
        tt[hl][b] = u;
    }
    __syncthreads();
    unsigned short* cb = (unsigned short*)ctxB;
    #pragma unroll
    for (int q = 0; q < 16; ++q){
        int bn = q*4 + (tid>>6);
        int hl = tid & 63;
        cb[((size_t)i*NB + bn)*NHD + hb*64 + hl] = tt[hl][bn];
    }
}

__global__ __launch_bounds__(256) void k_gemm_M(
    const float* __restrict__ dWih,
    const float* __restrict__ linW,
    bf16* __restrict__ M){
    int g0 = blockIdx.x*64;
    int h0 = blockIdx.y*64;
    __shared__ float As[64][36];
    __shared__ float Bs[32][68];
    int tid = threadIdx.x, tx = tid & 15, ty = tid >> 4;
    float acc[4][4] = {};
    for (int k0 = 0; k0 < ND; k0 += 32){
        #pragma unroll
        for (int m = 0; m < 8; ++m){
            int idx = m*256 + tid;
            int row = idx >> 5, kk = idx & 31;
            As[row][kk] = dWih[(size_t)(g0+row)*ND + k0 + kk];
            int k2 = idx >> 6, hh2 = idx & 63;
            Bs[k2][hh2] = linW[(size_t)(k0+k2)*NHD + h0 + hh2];
        }
        __syncthreads();
        for (int k = 0; k < 32; ++k){
            float a[4];
            #pragma unroll
            for (int i = 0; i < 4; ++i) a[i] = As[ty*4+i][k];
            float4 b4 = *(const float4*)&Bs[k][tx*4];
            #pragma unroll
            for (int i = 0; i < 4; ++i){
                acc[i][0] += a[i]*b4.x; acc[i][1] += a[i]*b4.y;
                acc[i][2] += a[i]*b4.z; acc[i][3] += a[i]*b4.w;
            }
        }
        __syncthreads();
    }
    #pragma unroll
    for (int i = 0; i < 4; ++i)
        #pragma unroll
        for (int j = 0; j < 4; ++j)
            M[(size_t)(g0+ty*4+i)*NHD + h0 + tx*4 + j] = __float2bfloat16(acc[i][j]);
}

// ---------------- MFMA prep GEMMs (double-tiled) ----------------
// 2 t per block: B-fragments reused -> total B traffic halved
__global__ __launch_bounds__(256, 2) void k_xg_mfma2(
    const bf16* __restrict__ xb,     // [64][256][512]
    const bf16* __restrict__ WihB,   // [4][1536][512]
    const float* __restrict__ b0, const float* __restrict__ b1,
    const float* __restrict__ b2, const float* __restrict__ b3,
    bf16* __restrict__ Xg){
    int t0 = blockIdx.x*2, gblk = blockIdx.y, dir = blockIdx.z;
    const float* bih = dir==0?b0:dir==1?b1:dir==2?b2:b3;
    int tid = threadIdx.x;
    int lane = tid & 63;
    int w = __builtin_amdgcn_readfirstlane(tid >> 6);
    int ln = lane & 15, lk = lane >> 4;
    int g = gblk*64 + w*16 + ln;
    const unsigned short* Bp = (const unsigned short*)WihB + ((size_t)(dir*NGE + g))*512 + lk*8;
    s8v Bf[16];
    #pragma unroll
    for (int q = 0; q < 16; ++q) Bf[q] = *(const s8v*)(Bp + q*32);
    float bi = bih[g];
    const unsigned short* xu = (const unsigned short*)xb;
    for (int tt = 0; tt < 2; ++tt){
        int t = t0 + tt;
        f32x4 C[4] = {};
        #pragma unroll
        for (int m = 0; m < 4; ++m){
            const unsigned short* Ap = xu + ((size_t)(m*16+ln)*NS + t)*ND + lk*8;
            #pragma unroll
            for (int q = 0; q < 16; ++q){
                s8v Af = *(const s8v*)(Ap + q*32);
                C[m] = __builtin_amdgcn_mfma_f32_16x16x32_bf16(Af, Bf[q], C[m], 0, 0, 0);
            }
        }
        unsigned short* Op = (unsigned short*)Xg + ((size_t)(dir*NS + t)*NGE + g)*NB;
        #pragma unroll
        for (int m = 0; m < 4; ++m){
            ushort4 o;
            o.x = f2bu(C[m][0] + bi); o.y = f2bu(C[m][1] + bi);
            o.z = f2bu(C[m][2] + bi); o.w = f2bu(C[m][3] + bi);
            *(ushort4*)(Op + m*16 + lk*4) = o;
        }
    }
}

// 2 i per block, C[2][4] held across kc: B traffic halved
__global__ __launch_bounds__(256, 2) void k_gctx_mfma2(
    const bf16* __restrict__ ctxB,   // [256][64][1024]
    const bf16* __restrict__ dWhhB,  // [3072][1024]
    const float* __restrict__ bhh,
    bf16* __restrict__ Gctx){
    int i0 = blockIdx.x*2, gblk = blockIdx.y;
    int tid = threadIdx.x;
    int lane = tid & 63;
    int w = __builtin_amdgcn_readfirstlane(tid >> 6);
    int ln = lane & 15, lk = lane >> 4;
    int g = gblk*64 + w*16 + ln;
    f32x4 C[2][4] = {};
    const unsigned short* cu = (const unsigned short*)ctxB;
    const unsigned short* wu = (const unsigned short*)dWhhB;
    #pragma unroll
    for (int kc = 0; kc < 2; ++kc){
        const unsigned short* Bp = wu + (size_t)g*NHD + kc*512 + lk*8;
        s8v Bf[16];
        #pragma unroll
        for (int q = 0; q < 16; ++q) Bf[q] = *(const s8v*)(Bp + q*32);
        #pragma unroll
        for (int ii = 0; ii < 2; ++ii){
            #pragma unroll
            for (int m = 0; m < 4; ++m){
                const unsigned short* Ap = cu + ((size_t)(i0+ii)*NB + m*16+ln)*NHD + kc*512 + lk*8;
                #pragma unroll
                for (int q = 0; q < 16; ++q){
                    s8v Af = *(const s8v*)(Ap + q*32);
                    C[ii][m] = __builtin_amdgcn_mfma_f32_16x16x32_bf16(Af, Bf[q], C[ii][m], 0, 0, 0);
                }
            }
        }
    }
    float bi = bhh[g];
    #pragma unroll
    for (int ii = 0; ii < 2; ++ii){
        unsigned short* Op = (unsigned short*)Gctx + ((size_t)(i0+ii)*NGD + g)*NB;
        #pragma unroll
        for (int m = 0; m < 4; ++m){
            ushort4 o;
            o.x = f2bu(C[ii][m][0] + bi); o.y = f2bu(C[ii][m][1] + bi);
            o.z = f2bu(C[ii][m][2] + bi); o.w = f2bu(C[ii][m][3] + bi);
            *(ushort4*)(Op + m*16 + lk*4) = o;
        }
    }
}

__global__ __launch_bounds__(256, 2) void k_rec_mfma(
    const bf16* __restrict__ Ht,     // [256][64][1024]
    const bf16* __restrict__ linWB,  // [512][1024]
    const float* __restrict__ linb,
    float* __restrict__ outRec){
    int i = blockIdx.x, dblk = blockIdx.y;
    int tid = threadIdx.x;
    int lane = tid & 63;
    int w = __builtin_amdgcn_readfirstlane(tid >> 6);
    int ln = lane & 15, lk = lane >> 4;
    int d = dblk*64 + w*16 + ln;
    f32x4 C[4] = {};
    const unsigned short* hu = (const unsigned short*)Ht;
    const unsigned short* wu = (const unsigned short*)linWB;
    #pragma unroll
    for (int kc = 0; kc < 2; ++kc){
        const unsigned short* Bp = wu + (size_t)d*NHD + kc*512 + lk*8;
        s8v Bf[16];
        #pragma unroll
        for (int q = 0; q < 16; ++q) Bf[q] = *(const s8v*)(Bp + q*32);
        #pragma unroll
        for (int m = 0; m < 4; ++m){
            const unsigned short* Ap = hu + ((size_t)i*NB + m*16+ln)*NHD + kc*512 + lk*8;
            #pragma unroll
            for (int q = 0; q < 16; ++q){
                s8v Af = *(const s8v*)(Ap + q*32);
                C[m] = __builtin_amdgcn_mfma_f32_16x16x32_bf16(Af, Bf[q], C[m], 0, 0, 0);
            }
        }
    }
    float lb = linb[d];
    #pragma unroll
    for (int m = 0; m < 4; ++m)
        #pragma unroll
        for (int r = 0; r < 4; ++r){
            int b = m*16 + lk*4 + r;
            outRec[((size_t)b*NS + i)*ND + d] = C[m][r] + lb;
        }
}

// ---------------- MFMA recurrence kernels (v6 barrier, LLC exchange, bf16 history) ----------------
__global__ __launch_bounds__(256, 1) void k_enc14(
    const bf16* __restrict__ Xg,
    const bf16* __restrict__ WB,     // [4][1536][512] bf16
    const float* __restrict__ b0, const float* __restrict__ b1,
    const float* __restrict__ b2, const float* __restrict__ b3,
    bf16* __restrict__ hxh,          // [4][256][64][512] bf16 (history == exchange)
    unsigned int* __restrict__ bar){
    int wg  = blockIdx.x;
    int grp = wg & 15;
    int wl  = wg >> 4;
    int dir = grp >> 2;
    int bq  = grp & 3;
    int tid = threadIdx.x;
    int lane = tid & 63;
    int wid = __builtin_amdgcn_readfirstlane(tid >> 6);
    int jl = wid & 1, kh = wid >> 1;
    int jt = wl*2 + jl;
    int ln = lane & 15, lk = lane >> 4;
    int j  = jt*16 + ln;
    int b0v = bq*16 + lk*4;
    const float* bhh = dir==0?b0:dir==1?b1:dir==2?b2:b3;
    const unsigned short* WBu = (const unsigned short*)WB;
    s8v Bf[3][8];
    #pragma unroll
    for (int g = 0; g < 3; ++g)
        #pragma unroll
        for (int q = 0; q < 8; ++q)
            Bf[g][q] = *(const s8v*)(WBu + ((size_t)(dir*NGE + g*512 + j))*512 + (kh*8+q)*32 + lk*8);
    float br=0.f, bz=0.f, bn=0.f;
    if (kh == 0){ br = bhh[j]; bz = bhh[j+512]; bn = bhh[j+1024]; }
    float hp0=0.f, hp1=0.f, hp2=0.f, hp3=0.f;
    __shared__ float red[2][3][64][4];
    unsigned int* gb = bar + grp*64;
    const unsigned short* Xgu = (const unsigned short*)Xg;
    const unsigned short* hu = (const unsigned short*)hxh;
    ushort4 xr, xz, xn;
    if (kh == 0){
        int t0 = (dir & 1) ? 255 : 0;
        size_t xb_ = (size_t)(dir*NS + t0)*NGE;
        xr = *(const ushort4*)(Xgu + (xb_ + j)*NB + b0v);
        xz = *(const ushort4*)(Xgu + (xb_ + j + 512)*NB + b0v);
        xn = *(const ushort4*)(Xgu + (xb_ + j + 1024)*NB + b0v);
    }
    for (int t = 0; t < NS; ++t){
        int tcur = (dir & 1) ? (255 - t) : t;
        f32x4 C0 = {0.f,0.f,0.f,0.f}, C1 = {0.f,0.f,0.f,0.f}, C2 = {0.f,0.f,0.f,0.f};
        if (t > 0){
            int tprev = (dir & 1) ? (256 - t) : (t - 1);
            const unsigned short* hxr = hu
                + (((size_t)(dir*NS + tprev))*64 + bq*16 + ln)*512 + kh*256 + lk*8;
            int4v a0,a1,a2,a3,a4,a5,a6,a7;
            LOADX8(hxr, a0,a1,a2,a3,a4,a5,a6,a7)
            s8v Af;
            #define MF3(AV) Af = cast8(AV); \
                C0 = __builtin_amdgcn_mfma_f32_16x16x32_bf16(Af, Bf[0][__q], C0, 0, 0, 0); \
                C1 = __builtin_amdgcn_mfma_f32_16x16x32_bf16(Af, Bf[1][__q], C1, 0, 0, 0); \
                C2 = __builtin_amdgcn_mfma_f32_16x16x32_bf16(Af, Bf[2][__q], C2, 0, 0, 0);
            { enum {__q=0}; MF3(a0) } { enum {__q=1}; MF3(a1) }
            { enum {__q=2}; MF3(a2) } { enum {__q=3}; MF3(a3) }
            { enum {__q=4}; MF3(a4) } { enum {__q=5}; MF3(a5) }
            { enum {__q=6}; MF3(a6) } { enum {__q=7}; MF3(a7) }
            #undef MF3
        }
        if (kh == 1){
            *(f32x4*)&red[jl][0][lane][0] = C0;
            *(f32x4*)&red[jl][1][lane][0] = C1;
            *(f32x4*)&red[jl][2][lane][0] = C2;
        }
        __syncthreads();
        if (kh == 0){
            C0 += *(const f32x4*)&red[jl][0][lane][0];
            C1 += *(const f32x4*)&red[jl][1][lane][0];
            C2 += *(const f32x4*)&red[jl][2][lane][0];
            {
                float r_ = sigmf(b2f(xr.x) + C0[0] + br);
                float z_ = sigmf(b2f(xz.x) + C1[0] + bz);
                float n_ = tanhf(b2f(xn.x) + r_*(C2[0] + bn));
                hp0 = (1.f - z_)*n_ + z_*hp0;
            }
            {
                float r_ = sigmf(b2f(xr.y) + C0[1] + br);
                float z_ = sigmf(b2f(xz.y) + C1[1] + bz);
                float n_ = tanhf(b2f(xn.y) + r_*(C2[1] + bn));
                hp1 = (1.f - z_)*n_ + z_*hp1;
            }
            {
                float r_ = sigmf(b2f(xr.z) + C0[2] + br);
                float z_ = sigmf(b2f(xz.z) + C1[2] + bz);
                float n_ = tanhf(b2f(xn.z) + r_*(C2[2] + bn));
                hp2 = (1.f - z_)*n_ + z_*hp2;
            }
            {
                float r_ = sigmf(b2f(xr.w) + C0[3] + br);
                float z_ = sigmf(b2f(xz.w) + C1[3] + bz);
                float n_ = tanhf(b2f(xn.w) + r_*(C2[3] + bn));
                hp3 = (1.f - z_)*n_ + z_*hp3;
            }
            const unsigned short* hw = hu + ((size_t)(dir*NS + tcur))*64*512;
            st2_llc(hw + (size_t)(b0v+0)*512 + j, (unsigned int)f2bu(hp0));
            st2_llc(hw + (size_t)(b0v+1)*512 + j, (unsigned int)f2bu(hp1));
            st2_llc(hw + (size_t)(b0v+2)*512 + j, (unsigned int)f2bu(hp2));
            st2_llc(hw + (size_t)(b0v+3)*512 + j, (unsigned int)f2bu(hp3));
            if (t < NS-1){   // prefetch next step's read-only gates (cached loads)
                int tn = (dir & 1) ? (254 - t) : (t + 1);
                size_t xb_ = (size_t)(dir*NS + tn)*NGE;
                xr = *(const ushort4*)(Xgu + (xb_ + j)*NB + b0v);
                xz = *(const ushort4*)(Xgu + (xb_ + j + 512)*NB + b0v);
                xn = *(const ushort4*)(Xgu + (xb_ + j + 1024)*NB + b0v);
            }
        }
        if (t < NS-1) groupbar_flat(gb, t+1, 16);
    }
}

__global__ __launch_bounds__(256, 1) void k_dec14(
    const bf16* __restrict__ MB,     // [3072][1024] bf16
    const float* __restrict__ cvec,
    const float* __restrict__ dbih,
    const bf16* __restrict__ Gctx,
    const bf16* __restrict__ ctxT,
    bf16* __restrict__ Ht,           // [256][64][1024] bf16 history (LLC-coherent)
    unsigned int* __restrict__ bar){
    int wg  = blockIdx.x;
    int grp = wg & 3;
    int jt  = wg >> 2;
    int tid = threadIdx.x;
    int lane = tid & 63;
    int wid = __builtin_amdgcn_readfirstlane(tid >> 6);
    int ln = lane & 15, lk = lane >> 4;
    int j  = jt*16 + ln;
    int b0v = grp*16 + lk*4;
    const unsigned short* MBu = (const unsigned short*)MB;
    s8v Bf[3][8];
    #pragma unroll
    for (int g = 0; g < 3; ++g)
        #pragma unroll
        for (int q = 0; q < 8; ++q)
            Bf[g][q] = *(const s8v*)(MBu + ((size_t)(g*NHD + j))*NHD + wid*256 + q*32 + lk*8);
    float c0=0.f,c1=0.f,c2=0.f,d0v=0.f,d1v=0.f,d2v=0.f;
    if (wid == 0){
        c0 = cvec[j]; c1 = cvec[j+NHD]; c2 = cvec[j+2*NHD];
        d0v = dbih[j]; d1v = dbih[j+NHD]; d2v = dbih[j+2*NHD];
    }
    __shared__ float red[3][3][64][4];
    unsigned int* gb = bar + grp*512;
    int leaf = jt & 7;
    const unsigned short* Gu = (const unsigned short*)Gctx;
    const unsigned short* Cu = (const unsigned short*)ctxT;
    const unsigned short* hu = (const unsigned short*)Ht;
    ushort4 gr, gz, gn, cx;
    if (wid == 0){
        gr = *(const ushort4*)(Gu + (size_t)j*NB + b0v);
        gz = *(const ushort4*)(Gu + (size_t)(j+NHD)*NB + b0v);
        gn = *(const ushort4*)(Gu + (size_t)(j+2*NHD)*NB + b0v);
        cx = *(const ushort4*)(Cu + (size_t)j*NB + b0v);
    }
    for (int i = 0; i < NS; ++i){
        f32x4 C0 = {0.f,0.f,0.f,0.f}, C1 = {0.f,0.f,0.f,0.f}, C2 = {0.f,0.f,0.f,0.f};
        if (i > 0){
            const unsigned short* hxr = hu
                + ((size_t)(i-1)*NB + grp*16 + ln)*NHD + wid*256 + lk*8;
            int4v a0,a1,a2,a3,a4,a5,a6,a7;
            LOADX8(hxr, a0,a1,a2,a3,a4,a5,a6,a7)
            s8v Af;
            #define MF3(AV) Af = cast8(AV); \
                C0 = __builtin_amdgcn_mfma_f32_16x16x32_bf16(Af, Bf[0][__q], C0, 0, 0, 0); \
                C1 = __builtin_amdgcn_mfma_f32_16x16x32_bf16(Af, Bf[1][__q], C1, 0, 0, 0); \
                C2 = __builtin_amdgcn_mfma_f32_16x16x32_bf16(Af, Bf[2][__q], C2, 0, 0, 0);
            { enum {__q=0}; MF3(a0) } { enum {__q=1}; MF3(a1) }
            { enum {__q=2}; MF3(a2) } { enum {__q=3}; MF3(a3) }
            { enum {__q=4}; MF3(a4) } { enum {__q=5}; MF3(a5) }
            { enum {__q=6}; MF3(a6) } { enum {__q=7}; MF3(a7) }
            #undef MF3
        }
        if (wid != 0){
            *(f32x4*)&red[wid-1][0][lane][0] = C0;
            *(f32x4*)&red[wid-1][1][lane][0] = C1;
            *(f32x4*)&red[wid-1][2][lane][0] = C2;
        }
        __syncthreads();
        if (wid == 0){
            #pragma unroll
            for (int w = 0; w < 3; ++w){
                C0 += *(const f32x4*)&red[w][0][lane][0];
                C1 += *(const f32x4*)&red[w][1][lane][0];
                C2 += *(const f32x4*)&red[w][2][lane][0];
            }
            f32x4 ho;
            {
                float g0v = (i==0) ? d0v : C0[0] + c0;
                float g1v = (i==0) ? d1v : C1[0] + c1;
                float g2v = (i==0) ? d2v : C2[0] + c2;
                float r_ = sigmf(g0v + b2f(gr.x));
                float z_ = sigmf(g1v + b2f(gz.x));
                float n_ = tanhf(g2v + r_*b2f(gn.x));
                ho[0] = (1.f - z_)*n_ + z_*b2f(cx.x);
            }
            {
                float g0v = (i==0) ? d0v : C0[1] + c0;
                float g1v = (i==0) ? d1v : C1[1] + c1;
                float g2v = (i==0) ? d2v : C2[1] + c2;
                float r_ = sigmf(g0v + b2f(gr.y));
                float z_ = sigmf(g1v + b2f(gz.y));
                float n_ = tanhf(g2v + r_*b2f(gn.y));
                ho[1] = (1.f - z_)*n_ + z_*b2f(cx.y);
            }
            {
                float g0v = (i==0) ? d0v : C0[2] + c0;
                float g1v = (i==0) ? d1v : C1[2] + c1;
                float g2v = (i==0) ? d2v : C2[2] + c2;
                float r_ = sigmf(g0v + b2f(gr.z));
                float z_ = sigmf(g1v + b2f(gz.z));
                float n_ = tanhf(g2v + r_*b2f(gn.z));
                ho[2] = (1.f - z_)*n_ + z_*b2f(cx.z);
            }
            {
                float g0v = (i==0) ? d0v : C0[3] + c0;
                float g1v = (i==0) ? d1v : C1[3] + c1;
                float g2v = (i==0) ? d2v : C2[3] + c2;
                float r_ = sigmf(g0v + b2f(gr.w));
                float z_ = sigmf(g1v + b2f(gz.w));
                float n_ = tanhf(g2v + r_*b2f(gn.w));
                ho[3] = (1.f - z_)*n_ + z_*b2f(cx.w);
            }
            const unsigned short* hw = hu + (size_t)i*NB*NHD;
            st2_llc(hw + (size_t)(b0v+0)*NHD + j, (unsigned int)f2bu(ho[0]));
            st2_llc(hw + (size_t)(b0v+1)*NHD + j, (unsigned int)f2bu(ho[1]));
            st2_llc(hw + (size_t)(b0v+2)*NHD + j, (unsigned int)f2bu(ho[2]));
            st2_llc(hw + (size_t)(b0v+3)*NHD + j, (unsigned int)f2bu(ho[3]));
            if (i < NS-1){   // prefetch next step's read-only operands (cached)
                size_t gbx = (size_t)(i+1)*NGD*NB;
                gr = *(const ushort4*)(Gu + gbx + (size_t)j*NB + b0v);
                gz = *(const ushort4*)(Gu + gbx + (size_t)(j+NHD)*NB + b0v);
                gn = *(const ushort4*)(Gu + gbx + (size_t)(j+2*NHD)*NB + b0v);
                cx = *(const ushort4*)(Cu + ((size_t)(i+1)*NHD + j)*NB + b0v);
            }
        }
        if (i < NS-1) groupbar_tree(gb, i+1, leaf);
    }
}

// ---------------- host launcher ----------------
extern "C" void kernel_launch(void* const* d_in, const int* in_sizes, int n_in,
                              void* d_out, int out_size, void* d_ws, size_t ws_size,
                              hipStream_t stream){
    const float* x   = (const float*)d_in[0];
    const float* eps = (const float*)d_in[1];
    const float* Wih[4]; const float* Whh[4]; const float* bih[4]; const float* bhh[4];
    for (int d = 0; d < 4; ++d){
        Wih[d] = (const float*)d_in[2 + 4*d];
        Whh[d] = (const float*)d_in[3 + 4*d];
        bih[d] = (const float*)d_in[4 + 4*d];
        bhh[d] = (const float*)d_in[5 + 4*d];
    }
    const float* dWih  = (const float*)d_in[18];
    const float* dWhh  = (const float*)d_in[19];
    const float* dbih  = (const float*)d_in[20];
    const float* dbhh  = (const float*)d_in[21];
    const float* attnW = (const float*)d_in[22];
    const float* attnb = (const float*)d_in[23];
    const float* linW  = (const float*)d_in[24];
    const float* linb  = (const float*)d_in[25];

    float* out    = (float*)d_out;
    float* outRec = out;
    float* outMu  = out + 8388608;
    float* outLv  = out + 25165824;

    char* ws = (char*)d_ws;
    bf16*  Xg    = (bf16*)(ws + 0);              // ph0-1: 201326592
    bf16*  Gctx  = (bf16*)(ws + 0);              // ph2-3: 100663296
    bf16*  ctxB  = (bf16*)(ws + 100663296);      // ph2:   33554432 (inside dead Xg)
    bf16*  hxh   = (bf16*)(ws + 201326592);      // ph1-2: 67108864
    bf16*  zbuf  = (bf16*)(ws + 268435456);      // ph2:   33554432
    bf16*  ctxT  = (bf16*)(ws + 301989888);      // ph2-3: 33554432
    bf16*  Ht    = (bf16*)(ws + 335544320);      // ph3-4: 33554432
    bf16*  xb    = (bf16*)(ws + 369098752);      // ph0:   16777216
    bf16*  WihB  = (bf16*)(ws + 385875968);      // ph0:   6291456
    bf16*  WhhB  = (bf16*)(ws + 392167424);      // ph0-1: 6291456
    bf16*  MbufB = (bf16*)(ws + 398458880);      // 6291456
    bf16*  dWhhB = (bf16*)(ws + 404750336);      // ph2:   6291456
    bf16*  linWB = (bf16*)(ws + 411041792);      // 1048576
    float* sx    = (float*)(ws + 412090368);     // 65536
    float* esb   = (float*)(ws + 412155904);     // 65536
    float* Se    = (float*)(ws + 412221440);     // 4096
    float* Tbuf  = (float*)(ws + 412225536);     // 262144
    float* cvec  = (float*)(ws + 412487680);     // 12288
    unsigned int* barE = (unsigned int*)(ws + 412499968);  // 16384 (16 groups x 256B)
    unsigned int* barD = (unsigned int*)(ws + 412516352);  // 16384 (4 groups x 2KB tree)

    hipMemsetAsync(ws + 412499968, 0, 32768, stream);

    // phase 0: conversions + statics + Xg (MFMA)
    hipLaunchKernelGGL(k_cvtW, dim3(8192), dim3(256), 0, stream, x, xb);
    hipLaunchKernelGGL(k_cvtW4, dim3(768,4), dim3(256), 0, stream,
                       Wih[0], Wih[1], Wih[2], Wih[3], WihB);
    hipLaunchKernelGGL(k_cvtW4, dim3(768,4), dim3(256), 0, stream,
                       Whh[0], Whh[1], Whh[2], Whh[3], WhhB);
    hipLaunchKernelGGL(k_gemm_M, dim3(48,16), dim3(256), 0, stream, dWih, linW, MbufB);
    hipLaunchKernelGGL(k_cvec, dim3(768), dim3(256), 0, stream, dWih, linb, dbih, cvec);
    hipLaunchKernelGGL(k_sx, dim3(4096), dim3(256), 0, stream, x, attnW, attnb, sx);
    hipLaunchKernelGGL(k_softprep2, dim3(64), dim3(256), 0, stream, sx, esb, Se);
    hipLaunchKernelGGL(k_xg_mfma2, dim3(128,24,4), dim3(256), 0, stream,
                       xb, WihB, bih[0], bih[1], bih[2], bih[3], Xg);

    // phase 1: encoder recurrence (MFMA) -> hxh (bf16 history)
    {
        void* a[] = { (void*)&Xg, (void*)&WhhB,
                      (void*)&bhh[0], (void*)&bhh[1], (void*)&bhh[2], (void*)&bhh[3],
                      (void*)&hxh, (void*)&barE };
        hipLaunchCooperativeKernel((void*)k_enc14, dim3(256), dim3(256), a, 0, stream);
    }

    // phase 2: z, mu/logvar outputs, attention statics, Gctx (MFMA)
    hipLaunchKernelGGL(k_zexp3, dim3(4096), dim3(256), 0, stream, hxh, eps, zbuf);
    hipLaunchKernelGGL(k_outT2, dim3(256,8), dim3(256), 0, stream, hxh, outMu, outLv);
    hipLaunchKernelGGL(k_cvtW, dim3(3072), dim3(256), 0, stream, dWhh, dWhhB);
    hipLaunchKernelGGL(k_cvtW, dim3(512), dim3(256), 0, stream, linW, linWB);
    hipLaunchKernelGGL(k_T2, dim3(1024), dim3(256), 0, stream, zbuf, esb, Tbuf);
    hipLaunchKernelGGL(k_ctx3, dim3(4096), dim3(256), 0, stream, zbuf, esb, Se, Tbuf, ctxT, ctxB);
    hipLaunchKernelGGL(k_gctx_mfma2, dim3(128,48), dim3(256), 0, stream, ctxB, dWhhB, dbhh, Gctx);

    // phase 3: decoder recurrence (MFMA)
    {
        void* a[] = { (void*)&MbufB, (void*)&cvec, (void*)&dbih, (void*)&Gctx, (void*)&ctxT,
                      (void*)&Ht, (void*)&barD };
        hipLaunchCooperativeKernel((void*)k_dec14, dim3(256), dim3(256), a, 0, stream);
    }

    // phase 4: output projection (MFMA)
    hipLaunchKernelGGL(k_rec_mfma, dim3(256,8), dim3(256), 0, stream, Ht, linWB, linb, outRec);
}

// Round 15
// 3574.837 us; speedup vs baseline: 1.2030x; 1.0234x over previous
//
#include <hip/hip_runtime.h>
#include <hip/hip_bf16.h>

typedef __hip_bfloat16 bf16;
typedef __attribute__((ext_vector_type(8))) short s8v;
typedef __attribute__((ext_vector_type(4))) float f32x4;
typedef __attribute__((ext_vector_type(4))) int int4v;

#define NB 64
#define NS 256
#define ND 512
#define NHE 512
#define NHD 1024
#define NGE 1536
#define NGD 3072

static __device__ __forceinline__ float sigmf(float x){ return 1.0f/(1.0f+__expf(-x)); }
static __device__ __forceinline__ float b2f(unsigned short u){ return __uint_as_float(((unsigned int)u) << 16); }
static __device__ __forceinline__ unsigned short f2bu(float f){
    bf16 v = __float2bfloat16(f);
    return *reinterpret_cast<unsigned short*>(&v);
}
static __device__ __forceinline__ s8v cast8(int4v v){
    union { int4v i; s8v s; } u; u.i = v; return u.s;
}
// LLC-coherent 2-byte store (bypass L1/L2 -> memory-side Infinity Cache)
static __device__ __forceinline__ void st2_llc(const void* p, unsigned int v){
    asm volatile("global_store_short %0, %1, off sc0 sc1"
                 :: "v"((unsigned long long)(uintptr_t)p), "v"(v) : "memory");
}

// 8x 16B LLC-coherent loads + drain.
#define LOADX8(BASEP, A0,A1,A2,A3,A4,A5,A6,A7)                                   \
    asm volatile(                                                                \
        "global_load_dwordx4 %0, %8, off sc0 sc1\n\t"                            \
        "global_load_dwordx4 %1, %8, off offset:64 sc0 sc1\n\t"                  \
        "global_load_dwordx4 %2, %8, off offset:128 sc0 sc1\n\t"                 \
        "global_load_dwordx4 %3, %8, off offset:192 sc0 sc1\n\t"                 \
        "global_load_dwordx4 %4, %8, off offset:256 sc0 sc1\n\t"                 \
        "global_load_dwordx4 %5, %8, off offset:320 sc0 sc1\n\t"                 \
        "global_load_dwordx4 %6, %8, off offset:384 sc0 sc1\n\t"                 \
        "global_load_dwordx4 %7, %8, off offset:448 sc0 sc1\n\t"                 \
        "s_waitcnt vmcnt(0)"                                                     \
        : "=&v"(A0),"=&v"(A1),"=&v"(A2),"=&v"(A3),                               \
          "=&v"(A4),"=&v"(A5),"=&v"(A6),"=&v"(A7)                                \
        : "v"((unsigned long long)(uintptr_t)(BASEP)) : "memory");               \
    __builtin_amdgcn_sched_barrier(0);

// ---- encoder barrier (v6): 16 WGs poll the monotonic arrival counter.
static __device__ __forceinline__ void groupbar_flat(unsigned int* base, int step, int nwg){
    __syncthreads();
    if (threadIdx.x == 0){
        __hip_atomic_fetch_add(base, 1u, __ATOMIC_RELAXED, __HIP_MEMORY_SCOPE_AGENT);
        while ((int)__hip_atomic_load(base, __ATOMIC_RELAXED, __HIP_MEMORY_SCOPE_AGENT) < step*nwg)
            __builtin_amdgcn_s_sleep(1);
    }
    __syncthreads();
}
// ---- decoder barrier (v5, measured-best): leaf -> root -> write-once flag.
// leaf l at base[l*32], root at base[256], flag at base[288].
static __device__ __forceinline__ void groupbar_tree(unsigned int* base, int step, int leaf){
    __syncthreads();
    if (threadIdx.x == 0){
        unsigned int lo = __hip_atomic_fetch_add(base + leaf*32, 1u, __ATOMIC_RELAXED, __HIP_MEMORY_SCOPE_AGENT);
        if ((int)lo == step*8 - 1){
            unsigned int ro = __hip_atomic_fetch_add(base + 256, 1u, __ATOMIC_RELAXED, __HIP_MEMORY_SCOPE_AGENT);
            if ((int)ro == step*8 - 1)
                __hip_atomic_store(base + 288, (unsigned int)step, __ATOMIC_RELAXED, __HIP_MEMORY_SCOPE_AGENT);
        }
        while ((int)__hip_atomic_load(base + 288, __ATOMIC_RELAXED, __HIP_MEMORY_SCOPE_AGENT) < step)
            __builtin_amdgcn_s_sleep(1);
    }
    __syncthreads();
}

// ---------------- small prep kernels ----------------
__global__ __launch_bounds__(256) void k_sx(const float* __restrict__ x,
                                            const float* __restrict__ attnW,
                                            const float* __restrict__ attnb,
                                            float* __restrict__ sx){
    int row = blockIdx.x*4 + (threadIdx.x>>6);
    int lane = threadIdx.x & 63;
    float s = 0.f;
    for (int d = lane; d < ND; d += 64) s += x[(size_t)row*ND + d]*attnW[d];
    #pragma unroll
    for (int off = 32; off; off >>= 1) s += __shfl_down(s, off, 64);
    if (lane == 0) sx[row] = s + attnb[0];
}

__global__ __launch_bounds__(256) void k_cvec(const float* __restrict__ dWih,
                                              const float* __restrict__ linb,
                                              const float* __restrict__ dbih,
                                              float* __restrict__ cvec){
    int row = blockIdx.x*4 + (threadIdx.x>>6);
    int lane = threadIdx.x & 63;
    float s = 0.f;
    for (int d = lane; d < ND; d += 64) s += dWih[(size_t)row*ND + d]*linb[d];
    #pragma unroll
    for (int off = 32; off; off >>= 1) s += __shfl_down(s, off, 64);
    if (lane == 0) cvec[row] = s + dbih[row];
}

__global__ __launch_bounds__(256) void k_softprep2(const float* __restrict__ sx,
                                                   float* __restrict__ esb,
                                                   float* __restrict__ Se){
    int b = blockIdx.x, s = threadIdx.x;
    __shared__ float red[256];
    float v = sx[b*NS + s];
    red[s] = v; __syncthreads();
    for (int off = 128; off; off >>= 1){ if (s < off) red[s] = fmaxf(red[s], red[s+off]); __syncthreads(); }
    float mx = red[0]; __syncthreads();
    float ev = __expf(v - mx);
    esb[s*NB + b] = ev;
    red[s] = ev; __syncthreads();
    for (int off = 128; off; off >>= 1){ if (s < off) red[s] += red[s+off]; __syncthreads(); }
    if (s == 0) Se[b] = red[0];
}

__global__ __launch_bounds__(256) void k_cvtW(const float* __restrict__ W, bf16* __restrict__ o){
    size_t i = ((size_t)blockIdx.x*256 + threadIdx.x)*4;
    float4 v = *(const float4*)(W + i);
    o[i+0] = __float2bfloat16(v.x);
    o[i+1] = __float2bfloat16(v.y);
    o[i+2] = __float2bfloat16(v.z);
    o[i+3] = __float2bfloat16(v.w);
}

// 4 source matrices -> one packed bf16 buffer (y selects source)
__global__ __launch_bounds__(256) void k_cvtW4(
    const float* __restrict__ p0, const float* __restrict__ p1,
    const float* __restrict__ p2, const float* __restrict__ p3,
    bf16* __restrict__ o){
    int y = blockIdx.y;
    const float* W = (y==0)?p0:(y==1)?p1:(y==2)?p2:p3;
    size_t i = ((size_t)blockIdx.x*256 + threadIdx.x)*4;
    float4 v = *(const float4*)(W + i);
    bf16* d = o + (size_t)y*NGE*NHE;
    d[i+0] = __float2bfloat16(v.x);
    d[i+1] = __float2bfloat16(v.y);
    d[i+2] = __float2bfloat16(v.z);
    d[i+3] = __float2bfloat16(v.w);
}

// z[t][h][b] from bf16 history hxh[dir][t][b][j]
__global__ __launch_bounds__(256) void k_zexp3(const bf16* __restrict__ hxh,
                                               const float* __restrict__ eps,
                                               bf16* __restrict__ z){
    int t  = blockIdx.x >> 4;
    int hb = blockIdx.x & 15;
    int dmu = hb >> 3;
    int jm0 = (hb & 7)*64;
    const unsigned short* hu = (const unsigned short*)hxh;
    __shared__ unsigned short zt[64][66];
    int tid = threadIdx.x;
    #pragma unroll
    for (int q = 0; q < 16; ++q){
        int bb = q*4 + (tid>>6);
        int hc = tid & 63;
        float mu = b2f(hu[(((size_t)(dmu*NS) + t)*64 + bb)*512 + jm0 + hc]);
        float lv = b2f(hu[(((size_t)((2+dmu)*NS) + t)*64 + bb)*512 + jm0 + hc]);
        float ep = eps[((size_t)bb*NS + t)*NHD + hb*64 + hc];
        zt[bb][hc] = f2bu(mu + ep*__expf(0.5f*lv));
    }
    __syncthreads();
    unsigned short* zu = (unsigned short*)z;
    int b = tid & 63;
    #pragma unroll
    for (int q = 0; q < 16; ++q){
        int hl = q*4 + (tid>>6);
        zu[((size_t)t*NHD + hb*64 + hl)*NB + b] = zt[b][hl];
    }
}

// mu/logvar outputs: coalesced copy from hxh[dir][t][b][j]
__global__ __launch_bounds__(256) void k_outT2(const bf16* __restrict__ hxh,
                                               float* __restrict__ outMu,
                                               float* __restrict__ outLv){
    int t  = blockIdx.x;
    int b0 = blockIdx.y*8;
    const unsigned short* hu = (const unsigned short*)hxh;
    int tid = threadIdx.x;
    #pragma unroll
    for (int q = 0; q < 16; ++q){
        int idx = q*256 + tid;
        int sel = idx >> 11;           // 0=mu 1=lv
        int rem = idx & 2047;
        int bb  = b0 + (rem >> 8);
        int h   = (rem & 255)*4;
        int dirn = (h >> 9) + sel*2;
        int j   = h & 511;
        ushort4 v = *(const ushort4*)(hu + (((size_t)(dirn*NS) + t)*64 + bb)*512 + j);
        float4 o;
        o.x = b2f(v.x); o.y = b2f(v.y); o.z = b2f(v.z); o.w = b2f(v.w);
        float* outp = sel ? outLv : outMu;
        *(float4*)(outp + ((size_t)bb*NS + t)*NHD + h) = o;
    }
}

__global__ __launch_bounds__(256) void k_T2(const bf16* __restrict__ z,
                                            const float* __restrict__ esb,
                                            float* __restrict__ T){
    int h = blockIdx.x;
    int b = threadIdx.x & 63;
    int sq = threadIdx.x >> 6;
    __shared__ float red[4][64];
    float acc = 0.f;
    #pragma unroll 8
    for (int s = sq*64; s < sq*64 + 64; ++s)
        acc += esb[s*NB + b]*__bfloat162float(z[((size_t)s*NHD + h)*NB + b]);
    red[sq][b] = acc; __syncthreads();
    if (sq == 0) T[h*NB + b] = red[0][b] + red[1][b] + red[2][b] + red[3][b];
}

__global__ __launch_bounds__(256) void k_ctx3(const bf16* __restrict__ z,
                                              const float* __restrict__ esb,
                                              const float* __restrict__ Se,
                                              const float* __restrict__ T,
                                              bf16* __restrict__ ctxT,
                                              bf16* __restrict__ ctxB){
    int i  = blockIdx.x >> 4;
    int hb = blockIdx.x & 15;
    int tid = threadIdx.x;
    int b  = tid & 63;
    __shared__ unsigned short tt[64][66];
    float ei  = esb[i*NB + b];
    float inv = 1.0f/(Se[b] - ei);
    #pragma unroll
    for (int q = 0; q < 16; ++q){
        int hl = q*4 + (tid>>6);
        int h = hb*64 + hl;
        float zv = __bfloat162float(z[((size_t)i*NHD + h)*NB + b]);
        float cv = (T[h*NB + b] - ei*zv)*inv;
        unsigned short u = f2bu(cv);
        ctxT[((size_t)i*NHD + h)*NB + b] = *reinterpret_cast<bf16*>(&u);
        tt[hl][b] = u;
    }
    __syncthreads();
    unsigned short* cb = (unsigned short*)ctxB;
    #pragma unroll
    for (int q = 0; q < 16; ++q){
        int bn = q*4 + (tid>>6);
        int hl = tid & 63;
        cb[((size_t)i*NB + bn)*NHD + hb*64 + hl] = tt[hl][bn];
    }
}

__global__ __launch_bounds__(256) void k_gemm_M(
    const float* __restrict__ dWih,
    const float* __restrict__ linW,
    bf16* __restrict__ M){
    int g0 = blockIdx.x*64;
    int h0 = blockIdx.y*64;
    __shared__ float As[64][36];
    __shared__ float Bs[32][68];
    int tid = threadIdx.x, tx = tid & 15, ty = tid >> 4;
    float acc[4][4] = {};
    for (int k0 = 0; k0 < ND; k0 += 32){
        #pragma unroll
        for (int m = 0; m < 8; ++m){
            int idx = m*256 + tid;
            int row = idx >> 5, kk = idx & 31;
            As[row][kk] = dWih[(size_t)(g0+row)*ND + k0 + kk];
            int k2 = idx >> 6, hh2 = idx & 63;
            Bs[k2][hh2] = linW[(size_t)(k0+k2)*NHD + h0 + hh2];
        }
        __syncthreads();
        for (int k = 0; k < 32; ++k){
            float a[4];
            #pragma unroll
            for (int i = 0; i < 4; ++i) a[i] = As[ty*4+i][k];
            float4 b4 = *(const float4*)&Bs[k][tx*4];
            #pragma unroll
            for (int i = 0; i < 4; ++i){
                acc[i][0] += a[i]*b4.x; acc[i][1] += a[i]*b4.y;
                acc[i][2] += a[i]*b4.z; acc[i][3] += a[i]*b4.w;
            }
        }
        __syncthreads();
    }
    #pragma unroll
    for (int i = 0; i < 4; ++i)
        #pragma unroll
        for (int j = 0; j < 4; ++j)
            M[(size_t)(g0+ty*4+i)*NHD + h0 + tx*4 + j] = __float2bfloat16(acc[i][j]);
}

// ---------------- MFMA prep GEMMs (double-tiled) ----------------
__global__ __launch_bounds__(256, 2) void k_xg_mfma2(
    const bf16* __restrict__ xb,     // [64][256][512]
    const bf16* __restrict__ WihB,   // [4][1536][512]
    const float* __restrict__ b0, const float* __restrict__ b1,
    const float* __restrict__ b2, const float* __restrict__ b3,
    bf16* __restrict__ Xg){
    int t0 = blockIdx.x*2, gblk = blockIdx.y, dir = blockIdx.z;
    const float* bih = dir==0?b0:dir==1?b1:dir==2?b2:b3;
    int tid = threadIdx.x;
    int lane = tid & 63;
    int w = __builtin_amdgcn_readfirstlane(tid >> 6);
    int ln = lane & 15, lk = lane >> 4;
    int g = gblk*64 + w*16 + ln;
    const unsigned short* Bp = (const unsigned short*)WihB + ((size_t)(dir*NGE + g))*512 + lk*8;
    s8v Bf[16];
    #pragma unroll
    for (int q = 0; q < 16; ++q) Bf[q] = *(const s8v*)(Bp + q*32);
    float bi = bih[g];
    const unsigned short* xu = (const unsigned short*)xb;
    for (int tt = 0; tt < 2; ++tt){
        int t = t0 + tt;
        f32x4 C[4] = {};
        #pragma unroll
        for (int m = 0; m < 4; ++m){
            const unsigned short* Ap = xu + ((size_t)(m*16+ln)*NS + t)*ND + lk*8;
            #pragma unroll
            for (int q = 0; q < 16; ++q){
                s8v Af = *(const s8v*)(Ap + q*32);
                C[m] = __builtin_amdgcn_mfma_f32_16x16x32_bf16(Af, Bf[q], C[m], 0, 0, 0);
            }
        }
        unsigned short* Op = (unsigned short*)Xg + ((size_t)(dir*NS + t)*NGE + g)*NB;
        #pragma unroll
        for (int m = 0; m < 4; ++m){
            ushort4 o;
            o.x = f2bu(C[m][0] + bi); o.y = f2bu(C[m][1] + bi);
            o.z = f2bu(C[m][2] + bi); o.w = f2bu(C[m][3] + bi);
            *(ushort4*)(Op + m*16 + lk*4) = o;
        }
    }
}

__global__ __launch_bounds__(256, 2) void k_gctx_mfma2(
    const bf16* __restrict__ ctxB,   // [256][64][1024]
    const bf16* __restrict__ dWhhB,  // [3072][1024]
    const float* __restrict__ bhh,
    bf16* __restrict__ Gctx){
    int i0 = blockIdx.x*2, gblk = blockIdx.y;
    int tid = threadIdx.x;
    int lane = tid & 63;
    int w = __builtin_amdgcn_readfirstlane(tid >> 6);
    int ln = lane & 15, lk = lane >> 4;
    int g = gblk*64 + w*16 + ln;
    f32x4 C[2][4] = {};
    const unsigned short* cu = (const unsigned short*)ctxB;
    const unsigned short* wu = (const unsigned short*)dWhhB;
    #pragma unroll
    for (int kc = 0; kc < 2; ++kc){
        const unsigned short* Bp = wu + (size_t)g*NHD + kc*512 + lk*8;
        s8v Bf[16];
        #pragma unroll
        for (int q = 0; q < 16; ++q) Bf[q] = *(const s8v*)(Bp + q*32);
        #pragma unroll
        for (int ii = 0; ii < 2; ++ii){
            #pragma unroll
            for (int m = 0; m < 4; ++m){
                const unsigned short* Ap = cu + ((size_t)(i0+ii)*NB + m*16+ln)*NHD + kc*512 + lk*8;
                #pragma unroll
                for (int q = 0; q < 16; ++q){
                    s8v Af = *(const s8v*)(Ap + q*32);
                    C[ii][m] = __builtin_amdgcn_mfma_f32_16x16x32_bf16(Af, Bf[q], C[ii][m], 0, 0, 0);
                }
            }
        }
    }
    float bi = bhh[g];
    #pragma unroll
    for (int ii = 0; ii < 2; ++ii){
        unsigned short* Op = (unsigned short*)Gctx + ((size_t)(i0+ii)*NGD + g)*NB;
        #pragma unroll
        for (int m = 0; m < 4; ++m){
            ushort4 o;
            o.x = f2bu(C[ii][m][0] + bi); o.y = f2bu(C[ii][m][1] + bi);
            o.z = f2bu(C[ii][m][2] + bi); o.w = f2bu(C[ii][m][3] + bi);
            *(ushort4*)(Op + m*16 + lk*4) = o;
        }
    }
}

__global__ __launch_bounds__(256, 2) void k_rec_mfma(
    const bf16* __restrict__ Ht,     // [256][64][1024]
    const bf16* __restrict__ linWB,  // [512][1024]
    const float* __restrict__ linb,
    float* __restrict__ outRec){
    int i = blockIdx.x, dblk = blockIdx.y;
    int tid = threadIdx.x;
    int lane = tid & 63;
    int w = __builtin_amdgcn_readfirstlane(tid >> 6);
    int ln = lane & 15, lk = lane >> 4;
    int d = dblk*64 + w*16 + ln;
    f32x4 C[4] = {};
    const unsigned short* hu = (const unsigned short*)Ht;
    const unsigned short* wu = (const unsigned short*)linWB;
    #pragma unroll
    for (int kc = 0; kc < 2; ++kc){
        const unsigned short* Bp = wu + (size_t)d*NHD + kc*512 + lk*8;
        s8v Bf[16];
        #pragma unroll
        for (int q = 0; q < 16; ++q) Bf[q] = *(const s8v*)(Bp + q*32);
        #pragma unroll
        for (int m = 0; m < 4; ++m){
            const unsigned short* Ap = hu + ((size_t)i*NB + m*16+ln)*NHD + kc*512 + lk*8;
            #pragma unroll
            for (int q = 0; q < 16; ++q){
                s8v Af = *(const s8v*)(Ap + q*32);
                C[m] = __builtin_amdgcn_mfma_f32_16x16x32_bf16(Af, Bf[q], C[m], 0, 0, 0);
            }
        }
    }
    float lb = linb[d];
    #pragma unroll
    for (int m = 0; m < 4; ++m)
        #pragma unroll
        for (int r = 0; r < 4; ++r){
            int b = m*16 + lk*4 + r;
            outRec[((size_t)b*NS + i)*ND + d] = C[m][r] + lb;
        }
}

// ---------------- MFMA recurrence kernels ----------------
__global__ __launch_bounds__(256, 1) void k_enc15(
    const bf16* __restrict__ Xg,
    const bf16* __restrict__ WB,     // [4][1536][512] bf16
    const float* __restrict__ b0, const float* __restrict__ b1,
    const float* __restrict__ b2, const float* __restrict__ b3,
    bf16* __restrict__ hxh,          // [4][256][64][512] bf16 (history == exchange)
    unsigned int* __restrict__ bar){
    int wg  = blockIdx.x;
    int grp = wg & 15;
    int wl  = wg >> 4;
    int dir = grp >> 2;
    int bq  = grp & 3;
    int tid = threadIdx.x;
    int lane = tid & 63;
    int wid = __builtin_amdgcn_readfirstlane(tid >> 6);
    int jl = wid & 1, kh = wid >> 1;
    int jt = wl*2 + jl;
    int ln = lane & 15, lk = lane >> 4;
    int j  = jt*16 + ln;
    int b0v = bq*16 + lk*4;
    const float* bhh = dir==0?b0:dir==1?b1:dir==2?b2:b3;
    const unsigned short* WBu = (const unsigned short*)WB;
    s8v Bf[3][8];
    #pragma unroll
    for (int g = 0; g < 3; ++g)
        #pragma unroll
        for (int q = 0; q < 8; ++q)
            Bf[g][q] = *(const s8v*)(WBu + ((size_t)(dir*NGE + g*512 + j))*512 + (kh*8+q)*32 + lk*8);
    float br=0.f, bz=0.f, bn=0.f;
    if (kh == 0){ br = bhh[j]; bz = bhh[j+512]; bn = bhh[j+1024]; }
    float hp0=0.f, hp1=0.f, hp2=0.f, hp3=0.f;
    __shared__ float red[2][3][64][4];
    unsigned int* gb = bar + grp*64;
    const unsigned short* Xgu = (const unsigned short*)Xg;
    const unsigned short* hu = (const unsigned short*)hxh;
    ushort4 xr, xz, xn;
    if (kh == 0){
        int t0 = (dir & 1) ? 255 : 0;
        size_t xb_ = (size_t)(dir*NS + t0)*NGE;
        xr = *(const ushort4*)(Xgu + (xb_ + j)*NB + b0v);
        xz = *(const ushort4*)(Xgu + (xb_ + j + 512)*NB + b0v);
        xn = *(const ushort4*)(Xgu + (xb_ + j + 1024)*NB + b0v);
    }
    for (int t = 0; t < NS; ++t){
        int tcur = (dir & 1) ? (255 - t) : t;
        f32x4 C0 = {0.f,0.f,0.f,0.f}, C1 = {0.f,0.f,0.f,0.f}, C2 = {0.f,0.f,0.f,0.f};
        if (t > 0){
            int tprev = (dir & 1) ? (256 - t) : (t - 1);
            const unsigned short* hxr = hu
                + (((size_t)(dir*NS + tprev))*64 + bq*16 + ln)*512 + kh*256 + lk*8;
            int4v a0,a1,a2,a3,a4,a5,a6,a7;
            LOADX8(hxr, a0,a1,a2,a3,a4,a5,a6,a7)
            s8v Af;
            #define MF3(AV) Af = cast8(AV); \
                C0 = __builtin_amdgcn_mfma_f32_16x16x32_bf16(Af, Bf[0][__q], C0, 0, 0, 0); \
                C1 = __builtin_amdgcn_mfma_f32_16x16x32_bf16(Af, Bf[1][__q], C1, 0, 0, 0); \
                C2 = __builtin_amdgcn_mfma_f32_16x16x32_bf16(Af, Bf[2][__q], C2, 0, 0, 0);
            { enum {__q=0}; MF3(a0) } { enum {__q=1}; MF3(a1) }
            { enum {__q=2}; MF3(a2) } { enum {__q=3}; MF3(a3) }
            { enum {__q=4}; MF3(a4) } { enum {__q=5}; MF3(a5) }
            { enum {__q=6}; MF3(a6) } { enum {__q=7}; MF3(a7) }
            #undef MF3
        }
        if (kh == 1){
            *(f32x4*)&red[jl][0][lane][0] = C0;
            *(f32x4*)&red[jl][1][lane][0] = C1;
            *(f32x4*)&red[jl][2][lane][0] = C2;
        }
        __syncthreads();
        if (kh == 0){
            C0 += *(const f32x4*)&red[jl][0][lane][0];
            C1 += *(const f32x4*)&red[jl][1][lane][0];
            C2 += *(const f32x4*)&red[jl][2][lane][0];
            {
                float r_ = sigmf(b2f(xr.x) + C0[0] + br);
                float z_ = sigmf(b2f(xz.x) + C1[0] + bz);
                float n_ = tanhf(b2f(xn.x) + r_*(C2[0] + bn));
                hp0 = (1.f - z_)*n_ + z_*hp0;
            }
            {
                float r_ = sigmf(b2f(xr.y) + C0[1] + br);
                float z_ = sigmf(b2f(xz.y) + C1[1] + bz);
                float n_ = tanhf(b2f(xn.y) + r_*(C2[1] + bn));
                hp1 = (1.f - z_)*n_ + z_*hp1;
            }
            {
                float r_ = sigmf(b2f(xr.z) + C0[2] + br);
                float z_ = sigmf(b2f(xz.z) + C1[2] + bz);
                float n_ = tanhf(b2f(xn.z) + r_*(C2[2] + bn));
                hp2 = (1.f - z_)*n_ + z_*hp2;
            }
            {
                float r_ = sigmf(b2f(xr.w) + C0[3] + br);
                float z_ = sigmf(b2f(xz.w) + C1[3] + bz);
                float n_ = tanhf(b2f(xn.w) + r_*(C2[3] + bn));
                hp3 = (1.f - z_)*n_ + z_*hp3;
            }
            const unsigned short* hw = hu + ((size_t)(dir*NS + tcur))*64*512;
            st2_llc(hw + (size_t)(b0v+0)*512 + j, (unsigned int)f2bu(hp0));
            st2_llc(hw + (size_t)(b0v+1)*512 + j, (unsigned int)f2bu(hp1));
            st2_llc(hw + (size_t)(b0v+2)*512 + j, (unsigned int)f2bu(hp2));
            st2_llc(hw + (size_t)(b0v+3)*512 + j, (unsigned int)f2bu(hp3));
            if (t < NS-1){   // prefetch next step's read-only gates (cached loads)
                int tn = (dir & 1) ? (254 - t) : (t + 1);
                size_t xb_ = (size_t)(dir*NS + tn)*NGE;
                xr = *(const ushort4*)(Xgu + (xb_ + j)*NB + b0v);
                xz = *(const ushort4*)(Xgu + (xb_ + j + 512)*NB + b0v);
                xn = *(const ushort4*)(Xgu + (xb_ + j + 1024)*NB + b0v);
            }
        }
        if (t < NS-1) groupbar_flat(gb, t+1, 16);
    }
}

__global__ __launch_bounds__(256, 1) void k_dec15(
    const bf16* __restrict__ MB,     // [3072][1024] bf16
    const float* __restrict__ cvec,
    const float* __restrict__ dbih,
    const bf16* __restrict__ Gctx,
    const bf16* __restrict__ ctxT,
    bf16* __restrict__ Ht,           // [256][64][1024] bf16 history (LLC-coherent)
    unsigned int* __restrict__ bar){
    int wg  = blockIdx.x;
    int grp = wg & 3;
    int jt  = wg >> 2;
    int tid = threadIdx.x;
    int lane = tid & 63;
    int wid = __builtin_amdgcn_readfirstlane(tid >> 6);
    int ln = lane & 15, lk = lane >> 4;
    int j  = jt*16 + ln;
    int b0v = grp*16 + lk*4;
    const unsigned short* MBu = (const unsigned short*)MB;
    s8v Bf[3][8];
    #pragma unroll
    for (int g = 0; g < 3; ++g)
        #pragma unroll
        for (int q = 0; q < 8; ++q)
            Bf[g][q] = *(const s8v*)(MBu + ((size_t)(g*NHD + j))*NHD + wid*256 + q*32 + lk*8);
    float c0=0.f,c1=0.f,c2=0.f,d0v=0.f,d1v=0.f,d2v=0.f;
    if (wid == 0){
        c0 = cvec[j]; c1 = cvec[j+NHD]; c2 = cvec[j+2*NHD];
        d0v = dbih[j]; d1v = dbih[j+NHD]; d2v = dbih[j+2*NHD];
    }
    __shared__ float red[3][3][64][4];
    unsigned int* gb = bar + grp*512;
    int leaf = jt & 7;
    const unsigned short* Gu = (const unsigned short*)Gctx;
    const unsigned short* Cu = (const unsigned short*)ctxT;
    const unsigned short* hu = (const unsigned short*)Ht;
    ushort4 gr, gz, gn, cx;
    if (wid == 0){
        gr = *(const ushort4*)(Gu + (size_t)j*NB + b0v);
        gz = *(const ushort4*)(Gu + (size_t)(j+NHD)*NB + b0v);
        gn = *(const ushort4*)(Gu + (size_t)(j+2*NHD)*NB + b0v);
        cx = *(const ushort4*)(Cu + (size_t)j*NB + b0v);
    }
    for (int i = 0; i < NS; ++i){
        f32x4 C0 = {0.f,0.f,0.f,0.f}, C1 = {0.f,0.f,0.f,0.f}, C2 = {0.f,0.f,0.f,0.f};
        if (i > 0){
            const unsigned short* hxr = hu
                + ((size_t)(i-1)*NB + grp*16 + ln)*NHD + wid*256 + lk*8;
            int4v a0,a1,a2,a3,a4,a5,a6,a7;
            LOADX8(hxr, a0,a1,a2,a3,a4,a5,a6,a7)
            s8v Af;
            #define MF3(AV) Af = cast8(AV); \
                C0 = __builtin_amdgcn_mfma_f32_16x16x32_bf16(Af, Bf[0][__q], C0, 0, 0, 0); \
                C1 = __builtin_amdgcn_mfma_f32_16x16x32_bf16(Af, Bf[1][__q], C1, 0, 0, 0); \
                C2 = __builtin_amdgcn_mfma_f32_16x16x32_bf16(Af, Bf[2][__q], C2, 0, 0, 0);
            { enum {__q=0}; MF3(a0) } { enum {__q=1}; MF3(a1) }
            { enum {__q=2}; MF3(a2) } { enum {__q=3}; MF3(a3) }
            { enum {__q=4}; MF3(a4) } { enum {__q=5}; MF3(a5) }
            { enum {__q=6}; MF3(a6) } { enum {__q=7}; MF3(a7) }
            #undef MF3
        }
        if (wid != 0){
            *(f32x4*)&red[wid-1][0][lane][0] = C0;
            *(f32x4*)&red[wid-1][1][lane][0] = C1;
            *(f32x4*)&red[wid-1][2][lane][0] = C2;
        }
        __syncthreads();
        if (wid == 0){
            #pragma unroll
            for (int w = 0; w < 3; ++w){
                C0 += *(const f32x4*)&red[w][0][lane][0];
                C1 += *(const f32x4*)&red[w][1][lane][0];
                C2 += *(const f32x4*)&red[w][2][lane][0];
            }
            f32x4 ho;
            {
                float g0v = (i==0) ? d0v : C0[0] + c0;
                float g1v = (i==0) ? d1v : C1[0] + c1;
                float g2v = (i==0) ? d2v : C2[0] + c2;
                float r_ = sigmf(g0v + b2f(gr.x));
                float z_ = sigmf(g1v + b2f(gz.x));
                float n_ = tanhf(g2v + r_*b2f(gn.x));
                ho[0] = (1.f - z_)*n_ + z_*b2f(cx.x);
            }
            {
                float g0v = (i==0) ? d0v : C0[1] + c0;
                float g1v = (i==0) ? d1v : C1[1] + c1;
                float g2v = (i==0) ? d2v : C2[1] + c2;
                float r_ = sigmf(g0v + b2f(gr.y));
                float z_ = sigmf(g1v + b2f(gz.y));
                float n_ = tanhf(g2v + r_*b2f(gn.y));
                ho[1] = (1.f - z_)*n_ + z_*b2f(cx.y);
            }
            {
                float g0v = (i==0) ? d0v : C0[2] + c0;
                float g1v = (i==0) ? d1v : C1[2] + c1;
                float g2v = (i==0) ? d2v : C2[2] + c2;
                float r_ = sigmf(g0v + b2f(gr.z));
                float z_ = sigmf(g1v + b2f(gz.z));
                float n_ = tanhf(g2v + r_*b2f(gn.z));
                ho[2] = (1.f - z_)*n_ + z_*b2f(cx.z);
            }
            {
                float g0v = (i==0) ? d0v : C0[3] + c0;
                float g1v = (i==0) ? d1v : C1[3] + c1;
                float g2v = (i==0) ? d2v : C2[3] + c2;
                float r_ = sigmf(g0v + b2f(gr.w));
                float z_ = sigmf(g1v + b2f(gz.w));
                float n_ = tanhf(g2v + r_*b2f(gn.w));
                ho[3] = (1.f - z_)*n_ + z_*b2f(cx.w);
            }
            const unsigned short* hw = hu + (size_t)i*NB*NHD;
            st2_llc(hw + (size_t)(b0v+0)*NHD + j, (unsigned int)f2bu(ho[0]));
            st2_llc(hw + (size_t)(b0v+1)*NHD + j, (unsigned int)f2bu(ho[1]));
            st2_llc(hw + (size_t)(b0v+2)*NHD + j, (unsigned int)f2bu(ho[2]));
            st2_llc(hw + (size_t)(b0v+3)*NHD + j, (unsigned int)f2bu(ho[3]));
            if (i < NS-1){   // prefetch next step's read-only operands (cached)
                size_t gbx = (size_t)(i+1)*NGD*NB;
                gr = *(const ushort4*)(Gu + gbx + (size_t)j*NB + b0v);
                gz = *(const ushort4*)(Gu + gbx + (size_t)(j+NHD)*NB + b0v);
                gn = *(const ushort4*)(Gu + gbx + (size_t)(j+2*NHD)*NB + b0v);
                cx = *(const ushort4*)(Cu + ((size_t)(i+1)*NHD + j)*NB + b0v);
            }
        }
        if (i < NS-1) groupbar_tree(gb, i+1, leaf);
    }
}

// ---------------- host launcher ----------------
extern "C" void kernel_launch(void* const* d_in, const int* in_sizes, int n_in,
                              void* d_out, int out_size, void* d_ws, size_t ws_size,
                              hipStream_t stream){
    const float* x   = (const float*)d_in[0];
    const float* eps = (const float*)d_in[1];
    const float* Wih[4]; const float* Whh[4]; const float* bih[4]; const float* bhh[4];
    for (int d = 0; d < 4; ++d){
        Wih[d] = (const float*)d_in[2 + 4*d];
        Whh[d] = (const float*)d_in[3 + 4*d];
        bih[d] = (const float*)d_in[4 + 4*d];
        bhh[d] = (const float*)d_in[5 + 4*d];
    }
    const float* dWih  = (const float*)d_in[18];
    const float* dWhh  = (const float*)d_in[19];
    const float* dbih  = (const float*)d_in[20];
    const float* dbhh  = (const float*)d_in[21];
    const float* attnW = (const float*)d_in[22];
    const float* attnb = (const float*)d_in[23];
    const float* linW  = (const float*)d_in[24];
    const float* linb  = (const float*)d_in[25];

    float* out    = (float*)d_out;
    float* outRec = out;
    float* outMu  = out + 8388608;
    float* outLv  = out + 25165824;

    char* ws = (char*)d_ws;
    bf16*  Xg    = (bf16*)(ws + 0);              // ph0-1: 201326592
    bf16*  Gctx  = (bf16*)(ws + 0);              // ph2-3: 100663296
    bf16*  ctxB  = (bf16*)(ws + 100663296);      // ph2:   33554432 (inside dead Xg)
    bf16*  hxh   = (bf16*)(ws + 201326592);      // ph1-2: 67108864
    bf16*  zbuf  = (bf16*)(ws + 268435456);      // ph2:   33554432
    bf16*  ctxT  = (bf16*)(ws + 301989888);      // ph2-3: 33554432
    bf16*  Ht    = (bf16*)(ws + 335544320);      // ph3-4: 33554432
    bf16*  xb    = (bf16*)(ws + 369098752);      // ph0:   16777216
    bf16*  WihB  = (bf16*)(ws + 385875968);      // ph0:   6291456
    bf16*  WhhB  = (bf16*)(ws + 392167424);      // ph0-1: 6291456
    bf16*  MbufB = (bf16*)(ws + 398458880);      // 6291456
    bf16*  dWhhB = (bf16*)(ws + 404750336);      // ph2:   6291456
    bf16*  linWB = (bf16*)(ws + 411041792);      // 1048576
    float* sx    = (float*)(ws + 412090368);     // 65536
    float* esb   = (float*)(ws + 412155904);     // 65536
    float* Se    = (float*)(ws + 412221440);     // 4096
    float* Tbuf  = (float*)(ws + 412225536);     // 262144
    float* cvec  = (float*)(ws + 412487680);     // 12288
    unsigned int* barE = (unsigned int*)(ws + 412499968);  // 16384 (16 groups x 256B)
    unsigned int* barD = (unsigned int*)(ws + 412516352);  // 16384 (4 groups x 2KB tree)

    hipMemsetAsync(ws + 412499968, 0, 32768, stream);

    // phase 0: conversions + statics + Xg (MFMA)
    hipLaunchKernelGGL(k_cvtW, dim3(8192), dim3(256), 0, stream, x, xb);
    hipLaunchKernelGGL(k_cvtW4, dim3(768,4), dim3(256), 0, stream,
                       Wih[0], Wih[1], Wih[2], Wih[3], WihB);
    hipLaunchKernelGGL(k_cvtW4, dim3(768,4), dim3(256), 0, stream,
                       Whh[0], Whh[1], Whh[2], Whh[3], WhhB);
    hipLaunchKernelGGL(k_gemm_M, dim3(48,16), dim3(256), 0, stream, dWih, linW, MbufB);
    hipLaunchKernelGGL(k_cvec, dim3(768), dim3(256), 0, stream, dWih, linb, dbih, cvec);
    hipLaunchKernelGGL(k_sx, dim3(4096), dim3(256), 0, stream, x, attnW, attnb, sx);
    hipLaunchKernelGGL(k_softprep2, dim3(64), dim3(256), 0, stream, sx, esb, Se);
    hipLaunchKernelGGL(k_xg_mfma2, dim3(128,24,4), dim3(256), 0, stream,
                       xb, WihB, bih[0], bih[1], bih[2], bih[3], Xg);

    // phase 1: encoder recurrence (MFMA) -> hxh (bf16 history)
    {
        void* a[] = { (void*)&Xg, (void*)&WhhB,
                      (void*)&bhh[0], (void*)&bhh[1], (void*)&bhh[2], (void*)&bhh[3],
                      (void*)&hxh, (void*)&barE };
        hipLaunchCooperativeKernel((void*)k_enc15, dim3(256), dim3(256), a, 0, stream);
    }

    // phase 2: z, mu/logvar outputs, attention statics, Gctx (MFMA)
    hipLaunchKernelGGL(k_zexp3, dim3(4096), dim3(256), 0, stream, hxh, eps, zbuf);
    hipLaunchKernelGGL(k_outT2, dim3(256,8), dim3(256), 0, stream, hxh, outMu, outLv);
    hipLaunchKernelGGL(k_cvtW, dim3(3072), dim3(256), 0, stream, dWhh, dWhhB);
    hipLaunchKernelGGL(k_cvtW, dim3(512), dim3(256), 0, stream, linW, linWB);
    hipLaunchKernelGGL(k_T2, dim3(1024), dim3(256), 0, stream, zbuf, esb, Tbuf);
    hipLaunchKernelGGL(k_ctx3, dim3(4096), dim3(256), 0, stream, zbuf, esb, Se, Tbuf, ctxT, ctxB);
    hipLaunchKernelGGL(k_gctx_mfma2, dim3(128,48), dim3(256), 0, stream, ctxB, dWhhB, dbhh, Gctx);

    // phase 3: decoder recurrence (MFMA)
    {
        void* a[] = { (void*)&MbufB, (void*)&cvec, (void*)&dbih, (void*)&Gctx, (void*)&ctxT,
                      (void*)&Ht, (void*)&barD };
        hipLaunchCooperativeKernel((void*)k_dec15, dim3(256), dim3(256), a, 0, stream);
    }

    // phase 4: output projection (MFMA)
    hipLaunchKernelGGL(k_rec_mfma, dim3(256,8), dim3(256), 0, stream, Ht, linWB, linb, outRec);
}

// Round 16
// 3570.685 us; speedup vs baseline: 1.2044x; 1.0012x over previous
//
#include <hip/hip_runtime.h>
#include <hip/hip_bf16.h>

typedef __hip_bfloat16 bf16;
typedef __attribute__((ext_vector_type(8))) short s8v;
typedef __attribute__((ext_vector_type(4))) float f32x4;
typedef __attribute__((ext_vector_type(4))) int int4v;

#define NB 64
#define NS 256
#define ND 512
#define NHE 512
#define NHD 1024
#define NGE 1536
#define NGD 3072

static __device__ __forceinline__ float sigmf(float x){ return 1.0f/(1.0f+__expf(-x)); }
static __device__ __forceinline__ float b2f(unsigned short u){ return __uint_as_float(((unsigned int)u) << 16); }
static __device__ __forceinline__ unsigned short f2bu(float f){
    bf16 v = __float2bfloat16(f);
    return *reinterpret_cast<unsigned short*>(&v);
}
static __device__ __forceinline__ s8v cast8(int4v v){
    union { int4v i; s8v s; } u; u.i = v; return u.s;
}
// LLC-coherent 2-byte store (bypass L1/L2 -> memory-side Infinity Cache)
static __device__ __forceinline__ void st2_llc(const void* p, unsigned int v){
    asm volatile("global_store_short %0, %1, off sc0 sc1"
                 :: "v"((unsigned long long)(uintptr_t)p), "v"(v) : "memory");
}

// 8x 16B LLC-coherent loads + drain.
#define LOADX8(BASEP, A0,A1,A2,A3,A4,A5,A6,A7)                                   \
    asm volatile(                                                                \
        "global_load_dwordx4 %0, %8, off sc0 sc1\n\t"                            \
        "global_load_dwordx4 %1, %8, off offset:64 sc0 sc1\n\t"                  \
        "global_load_dwordx4 %2, %8, off offset:128 sc0 sc1\n\t"                 \
        "global_load_dwordx4 %3, %8, off offset:192 sc0 sc1\n\t"                 \
        "global_load_dwordx4 %4, %8, off offset:256 sc0 sc1\n\t"                 \
        "global_load_dwordx4 %5, %8, off offset:320 sc0 sc1\n\t"                 \
        "global_load_dwordx4 %6, %8, off offset:384 sc0 sc1\n\t"                 \
        "global_load_dwordx4 %7, %8, off offset:448 sc0 sc1\n\t"                 \
        "s_waitcnt vmcnt(0)"                                                     \
        : "=&v"(A0),"=&v"(A1),"=&v"(A2),"=&v"(A3),                               \
          "=&v"(A4),"=&v"(A5),"=&v"(A6),"=&v"(A7)                                \
        : "v"((unsigned long long)(uintptr_t)(BASEP)) : "memory");               \
    __builtin_amdgcn_sched_barrier(0);

// ---- encoder barrier (v6): 16 WGs poll the monotonic arrival counter.
static __device__ __forceinline__ void groupbar_flat(unsigned int* base, int step, int nwg){
    __syncthreads();
    if (threadIdx.x == 0){
        __hip_atomic_fetch_add(base, 1u, __ATOMIC_RELAXED, __HIP_MEMORY_SCOPE_AGENT);
        while ((int)__hip_atomic_load(base, __ATOMIC_RELAXED, __HIP_MEMORY_SCOPE_AGENT) < step*nwg)
            __builtin_amdgcn_s_sleep(1);
    }
    __syncthreads();
}
// ---- decoder barrier (v5, measured-best): leaf -> root -> write-once flag.
static __device__ __forceinline__ void groupbar_tree(unsigned int* base, int step, int leaf){
    __syncthreads();
    if (threadIdx.x == 0){
        unsigned int lo = __hip_atomic_fetch_add(base + leaf*32, 1u, __ATOMIC_RELAXED, __HIP_MEMORY_SCOPE_AGENT);
        if ((int)lo == step*8 - 1){
            unsigned int ro = __hip_atomic_fetch_add(base + 256, 1u, __ATOMIC_RELAXED, __HIP_MEMORY_SCOPE_AGENT);
            if ((int)ro == step*8 - 1)
                __hip_atomic_store(base + 288, (unsigned int)step, __ATOMIC_RELAXED, __HIP_MEMORY_SCOPE_AGENT);
        }
        while ((int)__hip_atomic_load(base + 288, __ATOMIC_RELAXED, __HIP_MEMORY_SCOPE_AGENT) < step)
            __builtin_amdgcn_s_sleep(1);
    }
    __syncthreads();
}

// ---------------- small prep kernels ----------------
__global__ __launch_bounds__(256) void k_sx(const float* __restrict__ x,
                                            const float* __restrict__ attnW,
                                            const float* __restrict__ attnb,
                                            float* __restrict__ sx){
    int row = blockIdx.x*4 + (threadIdx.x>>6);
    int lane = threadIdx.x & 63;
    float s = 0.f;
    for (int d = lane; d < ND; d += 64) s += x[(size_t)row*ND + d]*attnW[d];
    #pragma unroll
    for (int off = 32; off; off >>= 1) s += __shfl_down(s, off, 64);
    if (lane == 0) sx[row] = s + attnb[0];
}

__global__ __launch_bounds__(256) void k_cvec(const float* __restrict__ dWih,
                                              const float* __restrict__ linb,
                                              const float* __restrict__ dbih,
                                              float* __restrict__ cvec){
    int row = blockIdx.x*4 + (threadIdx.x>>6);
    int lane = threadIdx.x & 63;
    float s = 0.f;
    for (int d = lane; d < ND; d += 64) s += dWih[(size_t)row*ND + d]*linb[d];
    #pragma unroll
    for (int off = 32; off; off >>= 1) s += __shfl_down(s, off, 64);
    if (lane == 0) cvec[row] = s + dbih[row];
}

__global__ __launch_bounds__(256) void k_softprep2(const float* __restrict__ sx,
                                                   float* __restrict__ esb,
                                                   float* __restrict__ Se){
    int b = blockIdx.x, s = threadIdx.x;
    __shared__ float red[256];
    float v = sx[b*NS + s];
    red[s] = v; __syncthreads();
    for (int off = 128; off; off >>= 1){ if (s < off) red[s] = fmaxf(red[s], red[s+off]); __syncthreads(); }
    float mx = red[0]; __syncthreads();
    float ev = __expf(v - mx);
    esb[s*NB + b] = ev;
    red[s] = ev; __syncthreads();
    for (int off = 128; off; off >>= 1){ if (s < off) red[s] += red[s+off]; __syncthreads(); }
    if (s == 0) Se[b] = red[0];
}

__global__ __launch_bounds__(256) void k_cvtW(const float* __restrict__ W, bf16* __restrict__ o){
    size_t i = ((size_t)blockIdx.x*256 + threadIdx.x)*4;
    float4 v = *(const float4*)(W + i);
    o[i+0] = __float2bfloat16(v.x);
    o[i+1] = __float2bfloat16(v.y);
    o[i+2] = __float2bfloat16(v.z);
    o[i+3] = __float2bfloat16(v.w);
}

// x[b][t][d] fp32 -> xt[t][b][d] bf16 (t-major for contiguous A-tiles)
__global__ __launch_bounds__(256) void k_cvtX(const float* __restrict__ x,
                                              bf16* __restrict__ xt){
    int t  = blockIdx.x;
    int d0 = blockIdx.y*64;
    int tid = threadIdx.x;
    #pragma unroll
    for (int q = 0; q < 16; ++q){
        int bb = q*4 + (tid>>6);
        int d  = d0 + (tid & 63);
        float v = x[((size_t)bb*NS + t)*ND + d];
        xt[((size_t)t*NB + bb)*ND + d] = __float2bfloat16(v);
    }
}

// 4 source matrices -> one packed bf16 buffer (y selects source)
__global__ __launch_bounds__(256) void k_cvtW4(
    const float* __restrict__ p0, const float* __restrict__ p1,
    const float* __restrict__ p2, const float* __restrict__ p3,
    bf16* __restrict__ o){
    int y = blockIdx.y;
    const float* W = (y==0)?p0:(y==1)?p1:(y==2)?p2:p3;
    size_t i = ((size_t)blockIdx.x*256 + threadIdx.x)*4;
    float4 v = *(const float4*)(W + i);
    bf16* d = o + (size_t)y*NGE*NHE;
    d[i+0] = __float2bfloat16(v.x);
    d[i+1] = __float2bfloat16(v.y);
    d[i+2] = __float2bfloat16(v.z);
    d[i+3] = __float2bfloat16(v.w);
}

// z[t][h][b] from bf16 history hxh[dir][t][b][j]
__global__ __launch_bounds__(256) void k_zexp3(const bf16* __restrict__ hxh,
                                               const float* __restrict__ eps,
                                               bf16* __restrict__ z){
    int t  = blockIdx.x >> 4;
    int hb = blockIdx.x & 15;
    int dmu = hb >> 3;
    int jm0 = (hb & 7)*64;
    const unsigned short* hu = (const unsigned short*)hxh;
    __shared__ unsigned short zt[64][66];
    int tid = threadIdx.x;
    #pragma unroll
    for (int q = 0; q < 16; ++q){
        int bb = q*4 + (tid>>6);
        int hc = tid & 63;
        float mu = b2f(hu[(((size_t)(dmu*NS) + t)*64 + bb)*512 + jm0 + hc]);
        float lv = b2f(hu[(((size_t)((2+dmu)*NS) + t)*64 + bb)*512 + jm0 + hc]);
        float ep = eps[((size_t)bb*NS + t)*NHD + hb*64 + hc];
        zt[bb][hc] = f2bu(mu + ep*__expf(0.5f*lv));
    }
    __syncthreads();
    unsigned short* zu = (unsigned short*)z;
    int b = tid & 63;
    #pragma unroll
    for (int q = 0; q < 16; ++q){
        int hl = q*4 + (tid>>6);
        zu[((size_t)t*NHD + hb*64 + hl)*NB + b] = zt[b][hl];
    }
}

// mu/logvar outputs: coalesced copy from hxh[dir][t][b][j]
__global__ __launch_bounds__(256) void k_outT2(const bf16* __restrict__ hxh,
                                               float* __restrict__ outMu,
                                               float* __restrict__ outLv){
    int t  = blockIdx.x;
    int b0 = blockIdx.y*8;
    const unsigned short* hu = (const unsigned short*)hxh;
    int tid = threadIdx.x;
    #pragma unroll
    for (int q = 0; q < 16; ++q){
        int idx = q*256 + tid;
        int sel = idx >> 11;           // 0=mu 1=lv
        int rem = idx & 2047;
        int bb  = b0 + (rem >> 8);
        int h   = (rem & 255)*4;
        int dirn = (h >> 9) + sel*2;
        int j   = h & 511;
        ushort4 v = *(const ushort4*)(hu + (((size_t)(dirn*NS) + t)*64 + bb)*512 + j);
        float4 o;
        o.x = b2f(v.x); o.y = b2f(v.y); o.z = b2f(v.z); o.w = b2f(v.w);
        float* outp = sel ? outLv : outMu;
        *(float4*)(outp + ((size_t)bb*NS + t)*NHD + h) = o;
    }
}

__global__ __launch_bounds__(256) void k_T2(const bf16* __restrict__ z,
                                            const float* __restrict__ esb,
                                            float* __restrict__ T){
    int h = blockIdx.x;
    int b = threadIdx.x & 63;
    int sq = threadIdx.x >> 6;
    __shared__ float red[4][64];
    float acc = 0.f;
    #pragma unroll 8
    for (int s = sq*64; s < sq*64 + 64; ++s)
        acc += esb[s*NB + b]*__bfloat162float(z[((size_t)s*NHD + h)*NB + b]);
    red[sq][b] = acc; __syncthreads();
    if (sq == 0) T[h*NB + b] = red[0][b] + red[1][b] + red[2][b] + red[3][b];
}

__global__ __launch_bounds__(256) void k_ctx3(const bf16* __restrict__ z,
                                              const float* __restrict__ esb,
                                              const float* __restrict__ Se,
                                              const float* __restrict__ T,
                                              bf16* __restrict__ ctxT,
                                              bf16* __restrict__ ctxB){
    int i  = blockIdx.x >> 4;
    int hb = blockIdx.x & 15;
    int tid = threadIdx.x;
    int b  = tid & 63;
    __shared__ unsigned short tt[64][66];
    float ei  = esb[i*NB + b];
    float inv = 1.0f/(Se[b] - ei);
    #pragma unroll
    for (int q = 0; q < 16; ++q){
        int hl = q*4 + (tid>>6);
        int h = hb*64 + hl;
        float zv = __bfloat162float(z[((size_t)i*NHD + h)*NB + b]);
        float cv = (T[h*NB + b] - ei*zv)*inv;
        unsigned short u = f2bu(cv);
        ctxT[((size_t)i*NHD + h)*NB + b] = *reinterpret_cast<bf16*>(&u);
        tt[hl][b] = u;
    }
    __syncthreads();
    unsigned short* cb = (unsigned short*)ctxB;
    #pragma unroll
    for (int q = 0; q < 16; ++q){
        int bn = q*4 + (tid>>6);
        int hl = tid & 63;
        cb[((size_t)i*NB + bn)*NHD + hb*64 + hl] = tt[hl][bn];
    }
}

__global__ __launch_bounds__(256) void k_gemm_M(
    const float* __restrict__ dWih,
    const float* __restrict__ linW,
    bf16* __restrict__ M){
    int g0 = blockIdx.x*64;
    int h0 = blockIdx.y*64;
    __shared__ float As[64][36];
    __shared__ float Bs[32][68];
    int tid = threadIdx.x, tx = tid & 15, ty = tid >> 4;
    float acc[4][4] = {};
    for (int k0 = 0; k0 < ND; k0 += 32){
        #pragma unroll
        for (int m = 0; m < 8; ++m){
            int idx = m*256 + tid;
            int row = idx >> 5, kk = idx & 31;
            As[row][kk] = dWih[(size_t)(g0+row)*ND + k0 + kk];
            int k2 = idx >> 6, hh2 = idx & 63;
            Bs[k2][hh2] = linW[(size_t)(k0+k2)*NHD + h0 + hh2];
        }
        __syncthreads();
        for (int k = 0; k < 32; ++k){
            float a[4];
            #pragma unroll
            for (int i = 0; i < 4; ++i) a[i] = As[ty*4+i][k];
            float4 b4 = *(const float4*)&Bs[k][tx*4];
            #pragma unroll
            for (int i = 0; i < 4; ++i){
                acc[i][0] += a[i]*b4.x; acc[i][1] += a[i]*b4.y;
                acc[i][2] += a[i]*b4.z; acc[i][3] += a[i]*b4.w;
            }
        }
        __syncthreads();
    }
    #pragma unroll
    for (int i = 0; i < 4; ++i)
        #pragma unroll
        for (int j = 0; j < 4; ++j)
            M[(size_t)(g0+ty*4+i)*NHD + h0 + tx*4 + j] = __float2bfloat16(acc[i][j]);
}

// ---------------- MFMA prep GEMMs ----------------
// A from xt[t][b][d] (contiguous per-t tile); 2 t per block (B reused)
__global__ __launch_bounds__(256, 2) void k_xg_mfma3(
    const bf16* __restrict__ xt,     // [256][64][512]
    const bf16* __restrict__ WihB,   // [4][1536][512]
    const float* __restrict__ b0, const float* __restrict__ b1,
    const float* __restrict__ b2, const float* __restrict__ b3,
    bf16* __restrict__ Xg){
    int t0 = blockIdx.x*2, gblk = blockIdx.y, dir = blockIdx.z;
    const float* bih = dir==0?b0:dir==1?b1:dir==2?b2:b3;
    int tid = threadIdx.x;
    int lane = tid & 63;
    int w = __builtin_amdgcn_readfirstlane(tid >> 6);
    int ln = lane & 15, lk = lane >> 4;
    int g = gblk*64 + w*16 + ln;
    const unsigned short* Bp = (const unsigned short*)WihB + ((size_t)(dir*NGE + g))*512 + lk*8;
    s8v Bf[16];
    #pragma unroll
    for (int q = 0; q < 16; ++q) Bf[q] = *(const s8v*)(Bp + q*32);
    float bi = bih[g];
    const unsigned short* xu = (const unsigned short*)xt;
    for (int tt = 0; tt < 2; ++tt){
        int t = t0 + tt;
        f32x4 C[4] = {};
        #pragma unroll
        for (int m = 0; m < 4; ++m){
            const unsigned short* Ap = xu + ((size_t)t*NB + m*16+ln)*ND + lk*8;
            #pragma unroll
            for (int q = 0; q < 16; ++q){
                s8v Af = *(const s8v*)(Ap + q*32);
                C[m] = __builtin_amdgcn_mfma_f32_16x16x32_bf16(Af, Bf[q], C[m], 0, 0, 0);
            }
        }
        unsigned short* Op = (unsigned short*)Xg + ((size_t)(dir*NS + t)*NGE + g)*NB;
        #pragma unroll
        for (int m = 0; m < 4; ++m){
            ushort4 o;
            o.x = f2bu(C[m][0] + bi); o.y = f2bu(C[m][1] + bi);
            o.z = f2bu(C[m][2] + bi); o.w = f2bu(C[m][3] + bi);
            *(ushort4*)(Op + m*16 + lk*4) = o;
        }
    }
}

__global__ __launch_bounds__(256, 2) void k_gctx_mfma2(
    const bf16* __restrict__ ctxB,   // [256][64][1024]
    const bf16* __restrict__ dWhhB,  // [3072][1024]
    const float* __restrict__ bhh,
    bf16* __restrict__ Gctx){
    int i0 = blockIdx.x*2, gblk = blockIdx.y;
    int tid = threadIdx.x;
    int lane = tid & 63;
    int w = __builtin_amdgcn_readfirstlane(tid >> 6);
    int ln = lane & 15, lk = lane >> 4;
    int g = gblk*64 + w*16 + ln;
    f32x4 C[2][4] = {};
    const unsigned short* cu = (const unsigned short*)ctxB;
    const unsigned short* wu = (const unsigned short*)dWhhB;
    #pragma unroll
    for (int kc = 0; kc < 2; ++kc){
        const unsigned short* Bp = wu + (size_t)g*NHD + kc*512 + lk*8;
        s8v Bf[16];
        #pragma unroll
        for (int q = 0; q < 16; ++q) Bf[q] = *(const s8v*)(Bp + q*32);
        #pragma unroll
        for (int ii = 0; ii < 2; ++ii){
            #pragma unroll
            for (int m = 0; m < 4; ++m){
                const unsigned short* Ap = cu + ((size_t)(i0+ii)*NB + m*16+ln)*NHD + kc*512 + lk*8;
                #pragma unroll
                for (int q = 0; q < 16; ++q){
                    s8v Af = *(const s8v*)(Ap + q*32);
                    C[ii][m] = __builtin_amdgcn_mfma_f32_16x16x32_bf16(Af, Bf[q], C[ii][m], 0, 0, 0);
                }
            }
        }
    }
    float bi = bhh[g];
    #pragma unroll
    for (int ii = 0; ii < 2; ++ii){
        unsigned short* Op = (unsigned short*)Gctx + ((size_t)(i0+ii)*NGD + g)*NB;
        #pragma unroll
        for (int m = 0; m < 4; ++m){
            ushort4 o;
            o.x = f2bu(C[ii][m][0] + bi); o.y = f2bu(C[ii][m][1] + bi);
            o.z = f2bu(C[ii][m][2] + bi); o.w = f2bu(C[ii][m][3] + bi);
            *(ushort4*)(Op + m*16 + lk*4) = o;
        }
    }
}

__global__ __launch_bounds__(256, 2) void k_rec_mfma(
    const bf16* __restrict__ Ht,     // [256][64][1024]
    const bf16* __restrict__ linWB,  // [512][1024]
    const float* __restrict__ linb,
    float* __restrict__ outRec){
    int i = blockIdx.x, dblk = blockIdx.y;
    int tid = threadIdx.x;
    int lane = tid & 63;
    int w = __builtin_amdgcn_readfirstlane(tid >> 6);
    int ln = lane & 15, lk = lane >> 4;
    int d = dblk*64 + w*16 + ln;
    f32x4 C[4] = {};
    const unsigned short* hu = (const unsigned short*)Ht;
    const unsigned short* wu = (const unsigned short*)linWB;
    #pragma unroll
    for (int kc = 0; kc < 2; ++kc){
        const unsigned short* Bp = wu + (size_t)d*NHD + kc*512 + lk*8;
        s8v Bf[16];
        #pragma unroll
        for (int q = 0; q < 16; ++q) Bf[q] = *(const s8v*)(Bp + q*32);
        #pragma unroll
        for (int m = 0; m < 4; ++m){
            const unsigned short* Ap = hu + ((size_t)i*NB + m*16+ln)*NHD + kc*512 + lk*8;
            #pragma unroll
            for (int q = 0; q < 16; ++q){
                s8v Af = *(const s8v*)(Ap + q*32);
                C[m] = __builtin_amdgcn_mfma_f32_16x16x32_bf16(Af, Bf[q], C[m], 0, 0, 0);
            }
        }
    }
    float lb = linb[d];
    #pragma unroll
    for (int m = 0; m < 4; ++m)
        #pragma unroll
        for (int r = 0; r < 4; ++r){
            int b = m*16 + lk*4 + r;
            outRec[((size_t)b*NS + i)*ND + d] = C[m][r] + lb;
        }
}

// ---------------- MFMA recurrence kernels ----------------
__global__ __launch_bounds__(256, 1) void k_enc16(
    const bf16* __restrict__ Xg,
    const bf16* __restrict__ WB,     // [4][1536][512] bf16
    const float* __restrict__ b0, const float* __restrict__ b1,
    const float* __restrict__ b2, const float* __restrict__ b3,
    bf16* __restrict__ hxh,          // [4][256][64][512] bf16 (history == exchange)
    unsigned int* __restrict__ bar){
    int wg  = blockIdx.x;
    int grp = wg & 15;
    int wl  = wg >> 4;
    int dir = grp >> 2;
    int bq  = grp & 3;
    int tid = threadIdx.x;
    int lane = tid & 63;
    int wid = __builtin_amdgcn_readfirstlane(tid >> 6);
    int jl = wid & 1, kh = wid >> 1;
    int jt = wl*2 + jl;
    int ln = lane & 15, lk = lane >> 4;
    int j  = jt*16 + ln;
    int b0v = bq*16 + lk*4;
    const float* bhh = dir==0?b0:dir==1?b1:dir==2?b2:b3;
    const unsigned short* WBu = (const unsigned short*)WB;
    s8v Bf[3][8];
    #pragma unroll
    for (int g = 0; g < 3; ++g)
        #pragma unroll
        for (int q = 0; q < 8; ++q)
            Bf[g][q] = *(const s8v*)(WBu + ((size_t)(dir*NGE + g*512 + j))*512 + (kh*8+q)*32 + lk*8);
    float br=0.f, bz=0.f, bn=0.f;
    if (kh == 0){ br = bhh[j]; bz = bhh[j+512]; bn = bhh[j+1024]; }
    float hp0=0.f, hp1=0.f, hp2=0.f, hp3=0.f;
    __shared__ float red[2][3][64][4];
    unsigned int* gb = bar + grp*64;
    const unsigned short* Xgu = (const unsigned short*)Xg;
    const unsigned short* hu = (const unsigned short*)hxh;
    ushort4 xr, xz, xn;
    if (kh == 0){
        int t0 = (dir & 1) ? 255 : 0;
        size_t xb_ = (size_t)(dir*NS + t0)*NGE;
        xr = *(const ushort4*)(Xgu + (xb_ + j)*NB + b0v);
        xz = *(const ushort4*)(Xgu + (xb_ + j + 512)*NB + b0v);
        xn = *(const ushort4*)(Xgu + (xb_ + j + 1024)*NB + b0v);
    }
    for (int t = 0; t < NS; ++t){
        int tcur = (dir & 1) ? (255 - t) : t;
        f32x4 C0 = {0.f,0.f,0.f,0.f}, C1 = {0.f,0.f,0.f,0.f}, C2 = {0.f,0.f,0.f,0.f};
        if (t > 0){
            int tprev = (dir & 1) ? (256 - t) : (t - 1);
            const unsigned short* hxr = hu
                + (((size_t)(dir*NS + tprev))*64 + bq*16 + ln)*512 + kh*256 + lk*8;
            int4v a0,a1,a2,a3,a4,a5,a6,a7;
            LOADX8(hxr, a0,a1,a2,a3,a4,a5,a6,a7)
            s8v Af;
            #define MF3(AV) Af = cast8(AV); \
                C0 = __builtin_amdgcn_mfma_f32_16x16x32_bf16(Af, Bf[0][__q], C0, 0, 0, 0); \
                C1 = __builtin_amdgcn_mfma_f32_16x16x32_bf16(Af, Bf[1][__q], C1, 0, 0, 0); \
                C2 = __builtin_amdgcn_mfma_f32_16x16x32_bf16(Af, Bf[2][__q], C2, 0, 0, 0);
            { enum {__q=0}; MF3(a0) } { enum {__q=1}; MF3(a1) }
            { enum {__q=2}; MF3(a2) } { enum {__q=3}; MF3(a3) }
            { enum {__q=4}; MF3(a4) } { enum {__q=5}; MF3(a5) }
            { enum {__q=6}; MF3(a6) } { enum {__q=7}; MF3(a7) }
            #undef MF3
        }
        if (kh == 1){
            *(f32x4*)&red[jl][0][lane][0] = C0;
            *(f32x4*)&red[jl][1][lane][0] = C1;
            *(f32x4*)&red[jl][2][lane][0] = C2;
        }
        __syncthreads();
        if (kh == 0){
            C0 += *(const f32x4*)&red[jl][0][lane][0];
            C1 += *(const f32x4*)&red[jl][1][lane][0];
            C2 += *(const f32x4*)&red[jl][2][lane][0];
            {
                float r_ = sigmf(b2f(xr.x) + C0[0] + br);
                float z_ = sigmf(b2f(xz.x) + C1[0] + bz);
                float n_ = tanhf(b2f(xn.x) + r_*(C2[0] + bn));
                hp0 = (1.f - z_)*n_ + z_*hp0;
            }
            {
                float r_ = sigmf(b2f(xr.y) + C0[1] + br);
                float z_ = sigmf(b2f(xz.y) + C1[1] + bz);
                float n_ = tanhf(b2f(xn.y) + r_*(C2[1] + bn));
                hp1 = (1.f - z_)*n_ + z_*hp1;
            }
            {
                float r_ = sigmf(b2f(xr.z) + C0[2] + br);
                float z_ = sigmf(b2f(xz.z) + C1[2] + bz);
                float n_ = tanhf(b2f(xn.z) + r_*(C2[2] + bn));
                hp2 = (1.f - z_)*n_ + z_*hp2;
            }
            {
                float r_ = sigmf(b2f(xr.w) + C0[3] + br);
                float z_ = sigmf(b2f(xz.w) + C1[3] + bz);
                float n_ = tanhf(b2f(xn.w) + r_*(C2[3] + bn));
                hp3 = (1.f - z_)*n_ + z_*hp3;
            }
            const unsigned short* hw = hu + ((size_t)(dir*NS + tcur))*64*512;
            st2_llc(hw + (size_t)(b0v+0)*512 + j, (unsigned int)f2bu(hp0));
            st2_llc(hw + (size_t)(b0v+1)*512 + j, (unsigned int)f2bu(hp1));
            st2_llc(hw + (size_t)(b0v+2)*512 + j, (unsigned int)f2bu(hp2));
            st2_llc(hw + (size_t)(b0v+3)*512 + j, (unsigned int)f2bu(hp3));
            if (t < NS-1){
                int tn = (dir & 1) ? (254 - t) : (t + 1);
                size_t xb_ = (size_t)(dir*NS + tn)*NGE;
                xr = *(const ushort4*)(Xgu + (xb_ + j)*NB + b0v);
                xz = *(const ushort4*)(Xgu + (xb_ + j + 512)*NB + b0v);
                xn = *(const ushort4*)(Xgu + (xb_ + j + 1024)*NB + b0v);
            }
        }
        if (t < NS-1) groupbar_flat(gb, t+1, 16);
    }
}

__global__ __launch_bounds__(256, 1) void k_dec16(
    const bf16* __restrict__ MB,     // [3072][1024] bf16
    const float* __restrict__ cvec,
    const float* __restrict__ dbih,
    const bf16* __restrict__ Gctx,
    const bf16* __restrict__ ctxT,
    bf16* __restrict__ Ht,           // [256][64][1024] bf16 history (LLC-coherent)
    unsigned int* __restrict__ bar){
    int wg  = blockIdx.x;
    int grp = wg & 3;
    int jt  = wg >> 2;
    int tid = threadIdx.x;
    int lane = tid & 63;
    int wid = __builtin_amdgcn_readfirstlane(tid >> 6);
    int ln = lane & 15, lk = lane >> 4;
    int j  = jt*16 + ln;
    int b0v = grp*16 + lk*4;
    const unsigned short* MBu = (const unsigned short*)MB;
    s8v Bf[3][8];
    #pragma unroll
    for (int g = 0; g < 3; ++g)
        #pragma unroll
        for (int q = 0; q < 8; ++q)
            Bf[g][q] = *(const s8v*)(MBu + ((size_t)(g*NHD + j))*NHD + wid*256 + q*32 + lk*8);
    float c0=0.f,c1=0.f,c2=0.f,d0v=0.f,d1v=0.f,d2v=0.f;
    if (wid == 0){
        c0 = cvec[j]; c1 = cvec[j+NHD]; c2 = cvec[j+2*NHD];
        d0v = dbih[j]; d1v = dbih[j+NHD]; d2v = dbih[j+2*NHD];
    }
    __shared__ float red[3][3][64][4];
    unsigned int* gb = bar + grp*512;
    int leaf = jt & 7;
    const unsigned short* Gu = (const unsigned short*)Gctx;
    const unsigned short* Cu = (const unsigned short*)ctxT;
    const unsigned short* hu = (const unsigned short*)Ht;
    ushort4 gr, gz, gn, cx;
    if (wid == 0){
        gr = *(const ushort4*)(Gu + (size_t)j*NB + b0v);
        gz = *(const ushort4*)(Gu + (size_t)(j+NHD)*NB + b0v);
        gn = *(const ushort4*)(Gu + (size_t)(j+2*NHD)*NB + b0v);
        cx = *(const ushort4*)(Cu + (size_t)j*NB + b0v);
    }
    for (int i = 0; i < NS; ++i){
        f32x4 C0 = {0.f,0.f,0.f,0.f}, C1 = {0.f,0.f,0.f,0.f}, C2 = {0.f,0.f,0.f,0.f};
        if (i > 0){
            const unsigned short* hxr = hu
                + ((size_t)(i-1)*NB + grp*16 + ln)*NHD + wid*256 + lk*8;
            int4v a0,a1,a2,a3,a4,a5,a6,a7;
            LOADX8(hxr, a0,a1,a2,a3,a4,a5,a6,a7)
            s8v Af;
            #define MF3(AV) Af = cast8(AV); \
                C0 = __builtin_amdgcn_mfma_f32_16x16x32_bf16(Af, Bf[0][__q], C0, 0, 0, 0); \
                C1 = __builtin_amdgcn_mfma_f32_16x16x32_bf16(Af, Bf[1][__q], C1, 0, 0, 0); \
                C2 = __builtin_amdgcn_mfma_f32_16x16x32_bf16(Af, Bf[2][__q], C2, 0, 0, 0);
            { enum {__q=0}; MF3(a0) } { enum {__q=1}; MF3(a1) }
            { enum {__q=2}; MF3(a2) } { enum {__q=3}; MF3(a3) }
            { enum {__q=4}; MF3(a4) } { enum {__q=5}; MF3(a5) }
            { enum {__q=6}; MF3(a6) } { enum {__q=7}; MF3(a7) }
            #undef MF3
        }
        if (wid != 0){
            *(f32x4*)&red[wid-1][0][lane][0] = C0;
            *(f32x4*)&red[wid-1][1][lane][0] = C1;
            *(f32x4*)&red[wid-1][2][lane][0] = C2;
        }
        __syncthreads();
        if (wid == 0){
            #pragma unroll
            for (int w = 0; w < 3; ++w){
                C0 += *(const f32x4*)&red[w][0][lane][0];
                C1 += *(const f32x4*)&red[w][1][lane][0];
                C2 += *(const f32x4*)&red[w][2][lane][0];
            }
            f32x4 ho;
            {
                float g0v = (i==0) ? d0v : C0[0] + c0;
                float g1v = (i==0) ? d1v : C1[0] + c1;
                float g2v = (i==0) ? d2v : C2[0] + c2;
                float r_ = sigmf(g0v + b2f(gr.x));
                float z_ = sigmf(g1v + b2f(gz.x));
                float n_ = tanhf(g2v + r_*b2f(gn.x));
                ho[0] = (1.f - z_)*n_ + z_*b2f(cx.x);
            }
            {
                float g0v = (i==0) ? d0v : C0[1] + c0;
                float g1v = (i==0) ? d1v : C1[1] + c1;
                float g2v = (i==0) ? d2v : C2[1] + c2;
                float r_ = sigmf(g0v + b2f(gr.y));
                float z_ = sigmf(g1v + b2f(gz.y));
                float n_ = tanhf(g2v + r_*b2f(gn.y));
                ho[1] = (1.f - z_)*n_ + z_*b2f(cx.y);
            }
            {
                float g0v = (i==0) ? d0v : C0[2] + c0;
                float g1v = (i==0) ? d1v : C1[2] + c1;
                float g2v = (i==0) ? d2v : C2[2] + c2;
                float r_ = sigmf(g0v + b2f(gr.z));
                float z_ = sigmf(g1v + b2f(gz.z));
                float n_ = tanhf(g2v + r_*b2f(gn.z));
                ho[2] = (1.f - z_)*n_ + z_*b2f(cx.z);
            }
            {
                float g0v = (i==0) ? d0v : C0[3] + c0;
                float g1v = (i==0) ? d1v : C1[3] + c1;
                float g2v = (i==0) ? d2v : C2[3] + c2;
                float r_ = sigmf(g0v + b2f(gr.w));
                float z_ = sigmf(g1v + b2f(gz.w));
                float n_ = tanhf(g2v + r_*b2f(gn.w));
                ho[3] = (1.f - z_)*n_ + z_*b2f(cx.w);
            }
            const unsigned short* hw = hu + (size_t)i*NB*NHD;
            st2_llc(hw + (size_t)(b0v+0)*NHD + j, (unsigned int)f2bu(ho[0]));
            st2_llc(hw + (size_t)(b0v+1)*NHD + j, (unsigned int)f2bu(ho[1]));
            st2_llc(hw + (size_t)(b0v+2)*NHD + j, (unsigned int)f2bu(ho[2]));
            st2_llc(hw + (size_t)(b0v+3)*NHD + j, (unsigned int)f2bu(ho[3]));
            if (i < NS-1){
                size_t gbx = (size_t)(i+1)*NGD*NB;
                gr = *(const ushort4*)(Gu + gbx + (size_t)j*NB + b0v);
                gz = *(const ushort4*)(Gu + gbx + (size_t)(j+NHD)*NB + b0v);
                gn = *(const ushort4*)(Gu + gbx + (size_t)(j+2*NHD)*NB + b0v);
                cx = *(const ushort4*)(Cu + ((size_t)(i+1)*NHD + j)*NB + b0v);
            }
        }
        if (i < NS-1) groupbar_tree(gb, i+1, leaf);
    }
}

// ---------------- host launcher ----------------
extern "C" void kernel_launch(void* const* d_in, const int* in_sizes, int n_in,
                              void* d_out, int out_size, void* d_ws, size_t ws_size,
                              hipStream_t stream){
    const float* x   = (const float*)d_in[0];
    const float* eps = (const float*)d_in[1];
    const float* Wih[4]; const float* Whh[4]; const float* bih[4]; const float* bhh[4];
    for (int d = 0; d < 4; ++d){
        Wih[d] = (const float*)d_in[2 + 4*d];
        Whh[d] = (const float*)d_in[3 + 4*d];
        bih[d] = (const float*)d_in[4 + 4*d];
        bhh[d] = (const float*)d_in[5 + 4*d];
    }
    const float* dWih  = (const float*)d_in[18];
    const float* dWhh  = (const float*)d_in[19];
    const float* dbih  = (const float*)d_in[20];
    const float* dbhh  = (const float*)d_in[21];
    const float* attnW = (const float*)d_in[22];
    const float* attnb = (const float*)d_in[23];
    const float* linW  = (const float*)d_in[24];
    const float* linb  = (const float*)d_in[25];

    float* out    = (float*)d_out;
    float* outRec = out;
    float* outMu  = out + 8388608;
    float* outLv  = out + 25165824;

    char* ws = (char*)d_ws;
    bf16*  Xg    = (bf16*)(ws + 0);              // ph0-1: 201326592
    bf16*  Gctx  = (bf16*)(ws + 0);              // ph2-3: 100663296
    bf16*  ctxB  = (bf16*)(ws + 100663296);      // ph2:   33554432 (inside dead Xg)
    bf16*  hxh   = (bf16*)(ws + 201326592);      // ph1-2: 67108864
    bf16*  zbuf  = (bf16*)(ws + 268435456);      // ph2:   33554432
    bf16*  ctxT  = (bf16*)(ws + 301989888);      // ph2-3: 33554432
    bf16*  Ht    = (bf16*)(ws + 335544320);      // ph3-4: 33554432
    bf16*  xt    = (bf16*)(ws + 369098752);      // ph0:   16777216 (t-major x)
    bf16*  WihB  = (bf16*)(ws + 385875968);      // ph0:   6291456
    bf16*  WhhB  = (bf16*)(ws + 392167424);      // ph0-1: 6291456
    bf16*  MbufB = (bf16*)(ws + 398458880);      // 6291456
    bf16*  dWhhB = (bf16*)(ws + 404750336);      // ph2:   6291456
    bf16*  linWB = (bf16*)(ws + 411041792);      // 1048576
    float* sx    = (float*)(ws + 412090368);     // 65536
    float* esb   = (float*)(ws + 412155904);     // 65536
    float* Se    = (float*)(ws + 412221440);     // 4096
    float* Tbuf  = (float*)(ws + 412225536);     // 262144
    float* cvec  = (float*)(ws + 412487680);     // 12288
    unsigned int* barE = (unsigned int*)(ws + 412499968);  // 16384
    unsigned int* barD = (unsigned int*)(ws + 412516352);  // 16384

    hipMemsetAsync(ws + 412499968, 0, 32768, stream);

    // phase 0: conversions + statics + Xg (MFMA)
    hipLaunchKernelGGL(k_cvtX, dim3(256,8), dim3(256), 0, stream, x, xt);
    hipLaunchKernelGGL(k_cvtW4, dim3(768,4), dim3(256), 0, stream,
                       Wih[0], Wih[1], Wih[2], Wih[3], WihB);
    hipLaunchKernelGGL(k_cvtW4, dim3(768,4), dim3(256), 0, stream,
                       Whh[0], Whh[1], Whh[2], Whh[3], WhhB);
    hipLaunchKernelGGL(k_gemm_M, dim3(48,16), dim3(256), 0, stream, dWih, linW, MbufB);
    hipLaunchKernelGGL(k_cvec, dim3(768), dim3(256), 0, stream, dWih, linb, dbih, cvec);
    hipLaunchKernelGGL(k_sx, dim3(4096), dim3(256), 0, stream, x, attnW, attnb, sx);
    hipLaunchKernelGGL(k_softprep2, dim3(64), dim3(256), 0, stream, sx, esb, Se);
    hipLaunchKernelGGL(k_xg_mfma3, dim3(128,24,4), dim3(256), 0, stream,
                       xt, WihB, bih[0], bih[1], bih[2], bih[3], Xg);

    // phase 1: encoder recurrence (MFMA) -> hxh (bf16 history)
    {
        void* a[] = { (void*)&Xg, (void*)&WhhB,
                      (void*)&bhh[0], (void*)&bhh[1], (void*)&bhh[2], (void*)&bhh[3],
                      (void*)&hxh, (void*)&barE };
        hipLaunchCooperativeKernel((void*)k_enc16, dim3(256), dim3(256), a, 0, stream);
    }

    // phase 2: z, mu/logvar outputs, attention statics, Gctx (MFMA)
    hipLaunchKernelGGL(k_zexp3, dim3(4096), dim3(256), 0, stream, hxh, eps, zbuf);
    hipLaunchKernelGGL(k_outT2, dim3(256,8), dim3(256), 0, stream, hxh, outMu, outLv);
    hipLaunchKernelGGL(k_cvtW, dim3(3072), dim3(256), 0, stream, dWhh, dWhhB);
    hipLaunchKernelGGL(k_cvtW, dim3(512), dim3(256), 0, stream, linW, linWB);
    hipLaunchKernelGGL(k_T2, dim3(1024), dim3(256), 0, stream, zbuf, esb, Tbuf);
    hipLaunchKernelGGL(k_ctx3, dim3(4096), dim3(256), 0, stream, zbuf, esb, Se, Tbuf, ctxT, ctxB);
    hipLaunchKernelGGL(k_gctx_mfma2, dim3(128,48), dim3(256), 0, stream, ctxB, dWhhB, dbhh, Gctx);

    // phase 3: decoder recurrence (MFMA)
    {
        void* a[] = { (void*)&MbufB, (void*)&cvec, (void*)&dbih, (void*)&Gctx, (void*)&ctxT,
                      (void*)&Ht, (void*)&barD };
        hipLaunchCooperativeKernel((void*)k_dec16, dim3(256), dim3(256), a, 0, stream);
    }

    // phase 4: output projection (MFMA)
    hipLaunchKernelGGL(k_rec_mfma, dim3(256,8), dim3(256), 0, stream, Ht, linWB, linb, outRec);
}